// Round 14
// baseline (195.404 us; speedup 1.0000x reference)
//
#include <hip/hip_runtime.h>
#include <hip/hip_fp16.h>

// Problem constants (fixed by setup_inputs)
constexpr int NB   = 4;
constexpr int SLEN = 5440;           // 64*64 + 32*32 + 16*16 + 8*8
constexpr long NTOK = (long)NB * SLEN; // 21760
constexpr int DD   = 256;
constexpr int NH   = 8;
constexpr int DHD  = 32;
constexpr int NL   = 4;
constexpr int NP   = 4;
constexpr int DFF  = 1024;

typedef __attribute__((ext_vector_type(8))) short short8;   // 8 x bf16
typedef __attribute__((ext_vector_type(8))) unsigned short ushort8;
typedef __attribute__((ext_vector_type(4))) float f32x4;

static __device__ __forceinline__ unsigned short f2bf(float x) {
  union { float f; unsigned int u; } v; v.f = x;
  unsigned int r = v.u + 0x7fffu + ((v.u >> 16) & 1u);   // RNE
  return (unsigned short)(r >> 16);
}
static __device__ __forceinline__ float bf2f(unsigned short u) {
  union { unsigned int i; float f; } v; v.i = ((unsigned int)u) << 16; return v.f;
}
static __device__ __forceinline__ unsigned int pack2bf(float lo, float hi) {
  return (unsigned int)f2bf(lo) | ((unsigned int)f2bf(hi) << 16);
}
static __device__ __forceinline__ unsigned int pack2h_dup(float a) {
  const unsigned int h = (unsigned int)__half_as_ushort(__float2half(a));
  return h | (h << 16);
}
static __device__ __forceinline__ __half2 u2h2(unsigned int u) {
  union { unsigned int i; __half2 h; } c; c.i = u; return c.h;
}

// B-fragment position for mfma_f32_16x16x32_bf16, weight K x N row-major.
// Dual-use: read as A-fragment it represents W^T (swapped-operand MFMA).
static __device__ __forceinline__ long fragpos(int k, int n, int KT) {
  const int kt = k >> 5, i = k & 7;
  const int lane = ((k >> 3) & 3) * 16 + (n & 15);
  const int nt = n >> 4;
  return (((long)(nt * KT + kt) * 64 + lane) * 8 + i);
}

// ---------------------------------------------------------------------------
// K_prep_all: fragment W1, W2, Wv, [Woff|Wattn], Wo into bf16 MFMA layout.
// ---------------------------------------------------------------------------
__global__ __launch_bounds__(256) void k_prep_all(const float* __restrict__ W1,
                                                  const float* __restrict__ W2,
                                                  const float* __restrict__ Wv,
                                                  const float* __restrict__ Woff,
                                                  const float* __restrict__ Wattn,
                                                  const float* __restrict__ Wo,
                                                  unsigned short* __restrict__ W1f,
                                                  unsigned short* __restrict__ W2f,
                                                  unsigned short* __restrict__ Wvf,
                                                  unsigned short* __restrict__ Wqf,
                                                  unsigned short* __restrict__ Wof) {
  const int g = blockIdx.x * 256 + threadIdx.x;
  if (g < 262144) {                       // W1: 256 x 1024, KT=8
    const int k = g >> 10, n = g & 1023;
    W1f[fragpos(k, n, 8)] = f2bf(W1[g]);
  } else if (g < 524288) {                // W2: 1024 x 256, KT=32
    const int g2 = g - 262144;
    const int k = g2 >> 8, n = g2 & 255;
    W2f[fragpos(k, n, 32)] = f2bf(W2[g2]);
  } else if (g < 589824) {                // Wv: 256 x 256, KT=8
    const int g2 = g - 524288;
    const int k = g2 >> 8, n = g2 & 255;
    Wvf[fragpos(k, n, 8)] = f2bf(Wv[g2]);
  } else if (g < 688128) {                // Wq fused: 256 x 384
    const int g2 = g - 589824;
    const int k = g2 / 384, n = g2 % 384;
    const float w = (n < 256) ? Woff[k * 256 + n] : Wattn[k * 128 + (n - 256)];
    Wqf[fragpos(k, n, 8)] = f2bf(w);
  } else if (g < 753664) {                // Wo: 256 x 256
    const int g2 = g - 688128;
    const int k = g2 >> 8, n = g2 & 255;
    Wof[fragpos(k, n, 8)] = f2bf(Wo[g2]);
  }
}

// ---------------------------------------------------------------------------
// K1+K2 fused (R13-proven): single 16KB LDS buffer.
// ---------------------------------------------------------------------------
__global__ __launch_bounds__(256) void k_vq2(const float* __restrict__ src,
                                             const float* __restrict__ pos,
                                             const unsigned short* __restrict__ Wvf,
                                             const float* __restrict__ bv,
                                             const unsigned short* __restrict__ Wqf,
                                             const float* __restrict__ boff,
                                             const float* __restrict__ battn,
                                             unsigned short* __restrict__ valh,
                                             unsigned short* __restrict__ offbf,
                                             float* __restrict__ attn) {
  __shared__ unsigned short Xs[32 * 256];   // 16 KB
  const int t = threadIdx.x;
  const int w = t >> 6, lane = t & 63;
  const int lr = lane & 15, lgrp = lane >> 4;
  const long row0 = (long)blockIdx.x * 32;
  const int r = t >> 3;
  const int c0 = (t & 7) * 32;

  {
    const float* sp = &src[(row0 + r) * DD + c0];
#pragma unroll
    for (int j = 0; j < 4; ++j) {
      const float4 a = *reinterpret_cast<const float4*>(&sp[j * 8 + 0]);
      const float4 b = *reinterpret_cast<const float4*>(&sp[j * 8 + 4]);
      short8 pk;
      pk[0] = (short)f2bf(a.x); pk[1] = (short)f2bf(a.y);
      pk[2] = (short)f2bf(a.z); pk[3] = (short)f2bf(a.w);
      pk[4] = (short)f2bf(b.x); pk[5] = (short)f2bf(b.y);
      pk[6] = (short)f2bf(b.z); pk[7] = (short)f2bf(b.w);
      int byte = r * 512 + (c0 + j * 8) * 2;
      byte ^= (r & 7) << 4;
      *reinterpret_cast<short8*>(reinterpret_cast<char*>(Xs) + byte) = pk;
    }
  }
  __syncthreads();

  short8 af[2][8];
#pragma unroll
  for (int mt = 0; mt < 2; ++mt)
#pragma unroll
    for (int kt = 0; kt < 8; ++kt) {
      const int row = mt * 16 + lr;
      int byte = row * 512 + kt * 64 + lgrp * 16;
      byte ^= (row & 7) << 4;
      af[mt][kt] = *reinterpret_cast<const short8*>(reinterpret_cast<const char*>(Xs) + byte);
    }

  // ---- phase V ----
  {
    f32x4 acc[2][4];
#pragma unroll
    for (int mt = 0; mt < 2; ++mt)
#pragma unroll
      for (int n = 0; n < 4; ++n) acc[mt][n] = (f32x4){0.f, 0.f, 0.f, 0.f};
#pragma unroll
    for (int n = 0; n < 4; ++n) {
      const int nt = w * 4 + n;
#pragma unroll
      for (int kt = 0; kt < 8; ++kt) {
        const short8 bf_ = *reinterpret_cast<const short8*>(&Wvf[((nt * 8 + kt) * 64 + lane) * 8]);
#pragma unroll
        for (int mt = 0; mt < 2; ++mt)
          acc[mt][n] = __builtin_amdgcn_mfma_f32_16x16x32_bf16(af[mt][kt], bf_, acc[mt][n], 0, 0, 0);
      }
    }
#pragma unroll
    for (int n = 0; n < 4; ++n) {
      const int col = w * 64 + n * 16 + lr;
      const float bb = bv[col];
#pragma unroll
      for (int mt = 0; mt < 2; ++mt)
#pragma unroll
        for (int j = 0; j < 4; ++j) {
          const int row = mt * 16 + lgrp * 4 + j;
          valh[(row0 + row) * DD + col] =
              __half_as_ushort(__float2half(acc[mt][n][j] + bb));
        }
    }
  }
  __syncthreads();

  // in-place Xs += pos
  {
    const float* pp = &pos[(row0 + r) * DD + c0];
#pragma unroll
    for (int j = 0; j < 4; ++j) {
      const float4 c = *reinterpret_cast<const float4*>(&pp[j * 8 + 0]);
      const float4 d = *reinterpret_cast<const float4*>(&pp[j * 8 + 4]);
      int byte = r * 512 + (c0 + j * 8) * 2;
      byte ^= (r & 7) << 4;
      short8 pk = *reinterpret_cast<const short8*>(reinterpret_cast<const char*>(Xs) + byte);
      pk[0] = (short)f2bf(bf2f((unsigned short)pk[0]) + c.x);
      pk[1] = (short)f2bf(bf2f((unsigned short)pk[1]) + c.y);
      pk[2] = (short)f2bf(bf2f((unsigned short)pk[2]) + c.z);
      pk[3] = (short)f2bf(bf2f((unsigned short)pk[3]) + c.w);
      pk[4] = (short)f2bf(bf2f((unsigned short)pk[4]) + d.x);
      pk[5] = (short)f2bf(bf2f((unsigned short)pk[5]) + d.y);
      pk[6] = (short)f2bf(bf2f((unsigned short)pk[6]) + d.z);
      pk[7] = (short)f2bf(bf2f((unsigned short)pk[7]) + d.w);
      *reinterpret_cast<short8*>(reinterpret_cast<char*>(Xs) + byte) = pk;
    }
  }
  __syncthreads();

#pragma unroll
  for (int mt = 0; mt < 2; ++mt)
#pragma unroll
    for (int kt = 0; kt < 8; ++kt) {
      const int row = mt * 16 + lr;
      int byte = row * 512 + kt * 64 + lgrp * 16;
      byte ^= (row & 7) << 4;
      af[mt][kt] = *reinterpret_cast<const short8*>(reinterpret_cast<const char*>(Xs) + byte);
    }

  // ---- phase Q ----
  {
    f32x4 acc[2][6];
#pragma unroll
    for (int mt = 0; mt < 2; ++mt)
#pragma unroll
      for (int i = 0; i < 6; ++i) acc[mt][i] = (f32x4){0.f, 0.f, 0.f, 0.f};
#pragma unroll
    for (int i = 0; i < 6; ++i) {
      const int ntg = w * 6 + i;
#pragma unroll
      for (int kt = 0; kt < 8; ++kt) {
        const short8 bf_ = *reinterpret_cast<const short8*>(&Wqf[((ntg * 8 + kt) * 64 + lane) * 8]);
#pragma unroll
        for (int mt = 0; mt < 2; ++mt)
          acc[mt][i] = __builtin_amdgcn_mfma_f32_16x16x32_bf16(af[mt][kt], bf_, acc[mt][i], 0, 0, 0);
      }
    }
#pragma unroll
    for (int i = 0; i < 6; ++i) {
      const int ntg = w * 6 + i;
      if (ntg < 16) {
        const int col = ntg * 16 + lr;
        const float bb = boff[col];
#pragma unroll
        for (int mt = 0; mt < 2; ++mt)
#pragma unroll
          for (int j = 0; j < 4; ++j) {
            const int row = mt * 16 + lgrp * 4 + j;
            offbf[(row0 + row) * 256 + col] = f2bf(acc[mt][i][j] + bb);
          }
      } else {
        const int na = ntg - 16;       // head index
        const float bb = battn[na * 16 + lr];
#pragma unroll
        for (int mt = 0; mt < 2; ++mt)
#pragma unroll
          for (int j = 0; j < 4; ++j) {
            const int row = mt * 16 + lgrp * 4 + j;
            const float v = acc[mt][i][j] + bb;
            float m = v;
#pragma unroll
            for (int d_ = 1; d_ <= 8; d_ <<= 1) m = fmaxf(m, __shfl_xor(m, d_, 16));
            const float e = __expf(v - m);
            float s = e;
#pragma unroll
            for (int d_ = 1; d_ <= 8; d_ <<= 1) s += __shfl_xor(s, d_, 16);
            attn[(row0 + row) * 128 + na * 16 + lr] = e / s;
          }
      }
    }
  }
}

// ---------------------------------------------------------------------------
// K3: deformable sampling v7 (R12-proven). FP16 value -> pure v_pk_fma_f16.
// ---------------------------------------------------------------------------
__global__ __launch_bounds__(256) void k_sample6(const unsigned short* __restrict__ valh,
                                                 const unsigned short* __restrict__ offbf,
                                                 const float* __restrict__ attn,
                                                 const float* __restrict__ refp,
                                                 unsigned short* __restrict__ src2bf) {
  __shared__ int4  sIdx[4][2][8][16];   // 16 KB
  __shared__ uint4 sWgt[4][2][8][16];   // 16 KB (4 x dup-half2)
  const int t = threadIdx.x;
  const int w = t >> 6, lane = t & 63;
  const int tok = lane >> 5, hg = (lane >> 2) & 7, li = lane & 3;
  const int B = blockIdx.x;
  const int bimg = (B & 7) >> 1;
  const int ii = ((B >> 3) << 1) + (B & 1);       // 0..679
  const long n = (long)bimg * SLEN + ii * 8 + w * 2 + tok;
  const long bOff = (long)bimg * SLEN;

  const int   WlA[4] = {64, 32, 16, 8};
  const float rWA[4] = {1.f / 64.f, 1.f / 32.f, 1.f / 16.f, 1.f / 8.f};
  const int   stA[4] = {0, 4096, 5120, 5376};

#pragma unroll
  for (int q = 0; q < 4; ++q) {       // level = q, point-in-level = li
    const int pt = q * 4 + li;
    const int Wi = WlA[q];
    const float Wf = (float)Wi, rW = rWA[q];
    const float rx = refp[(n * 4 + q) * 2 + 0];
    const float ry = refp[(n * 4 + q) * 2 + 1];
    const float aw = attn[n * 128 + hg * 16 + pt];
    const int oi = ((hg * 4 + q) * 4 + li) * 2;
    const unsigned int opk = *reinterpret_cast<const unsigned int*>(&offbf[n * 256 + oi]);
    const float ox = bf2f((unsigned short)(opk & 0xffff));
    const float oy = bf2f((unsigned short)(opk >> 16));
    const float px = (rx + ox * rW) * Wf - 0.5f;
    const float py = (ry + oy * rW) * Wf - 0.5f;
    const float x0f = floorf(px), y0f = floorf(py);
    const float fx = px - x0f, fy = py - y0f;
    const int x0 = (int)x0f, y0 = (int)y0f;
    int   ic[4];
    float wc[4];
#pragma unroll
    for (int c = 0; c < 4; ++c) {
      const int dx = c & 1, dy = c >> 1;
      const int xi = x0 + dx, yi = y0 + dy;
      const float cw = (dx ? fx : 1.f - fx) * (dy ? fy : 1.f - fy);
      const bool valid = (xi >= 0) && (xi < Wi) && (yi >= 0) && (yi < Wi);
      const int xc = min(max(xi, 0), Wi - 1);
      const int yc = min(max(yi, 0), Wi - 1);
      const long flat = stA[q] + yc * Wi + xc;
      ic[c] = (int)((bOff + flat) * DD + hg * DHD);
      wc[c] = aw * cw * (valid ? 1.f : 0.f);
    }
    const int slot = pt ^ hg;
    sIdx[w][tok][hg][slot] = make_int4(ic[0], ic[1], ic[2], ic[3]);
    sWgt[w][tok][hg][slot] = make_uint4(pack2h_dup(wc[0]), pack2h_dup(wc[1]),
                                        pack2h_dup(wc[2]), pack2h_dup(wc[3]));
  }
  __syncthreads();

  __half2 acc[4];
#pragma unroll
  for (int d = 0; d < 4; ++d) acc[d] = __float2half2_rn(0.f);
#pragma unroll 4
  for (int pt = 0; pt < 16; ++pt) {
    const int slot = pt ^ hg;
    const int4  ia = sIdx[w][tok][hg][slot];
    const uint4 wp = sWgt[w][tok][hg][slot];
    const uint4 u0 = *reinterpret_cast<const uint4*>(&valh[(long)ia.x + li * 8]);
    const uint4 u1 = *reinterpret_cast<const uint4*>(&valh[(long)ia.y + li * 8]);
    const uint4 u2 = *reinterpret_cast<const uint4*>(&valh[(long)ia.z + li * 8]);
    const uint4 u3 = *reinterpret_cast<const uint4*>(&valh[(long)ia.w + li * 8]);
    const __half2 w0 = u2h2(wp.x), w1 = u2h2(wp.y), w2 = u2h2(wp.z), w3 = u2h2(wp.w);
    acc[0] = __hfma2(u2h2(u0.x), w0, acc[0]);
    acc[1] = __hfma2(u2h2(u0.y), w0, acc[1]);
    acc[2] = __hfma2(u2h2(u0.z), w0, acc[2]);
    acc[3] = __hfma2(u2h2(u0.w), w0, acc[3]);
    acc[0] = __hfma2(u2h2(u1.x), w1, acc[0]);
    acc[1] = __hfma2(u2h2(u1.y), w1, acc[1]);
    acc[2] = __hfma2(u2h2(u1.z), w1, acc[2]);
    acc[3] = __hfma2(u2h2(u1.w), w1, acc[3]);
    acc[0] = __hfma2(u2h2(u2.x), w2, acc[0]);
    acc[1] = __hfma2(u2h2(u2.y), w2, acc[1]);
    acc[2] = __hfma2(u2h2(u2.z), w2, acc[2]);
    acc[3] = __hfma2(u2h2(u2.w), w2, acc[3]);
    acc[0] = __hfma2(u2h2(u3.x), w3, acc[0]);
    acc[1] = __hfma2(u2h2(u3.y), w3, acc[1]);
    acc[2] = __hfma2(u2h2(u3.z), w3, acc[2]);
    acc[3] = __hfma2(u2h2(u3.w), w3, acc[3]);
  }
  ushort8 o;
#pragma unroll
  for (int d = 0; d < 4; ++d) {
    o[2 * d]     = f2bf(__half2float(__low2half(acc[d])));
    o[2 * d + 1] = f2bf(__half2float(__high2half(acc[d])));
  }
  *reinterpret_cast<ushort8*>(&src2bf[n * DD + hg * DHD + li * 8]) = o;
}

// ---------------------------------------------------------------------------
// K_tail: out = LN2(x + relu(x@W1+b1)@W2 + b2), x = LN1(src + src2@Wo + bo).
// One block per 32 tokens (680 blocks), 4 waves, 80 KB LDS (2 blocks/CU).
// Phases: outproj(global A-frags) -> LN1 -> x in LDS -> FFN1 (swapped-op,
// h in LDS 64KB) -> FFN2 (streaming from LDS) -> LN2 -> out.
// Eliminates xbf + hbf HBM round trips (~120 MB).
// ---------------------------------------------------------------------------
__global__ __launch_bounds__(256) void k_tail(const unsigned short* __restrict__ src2bf,
                                              const unsigned short* __restrict__ Wof,
                                              const float* __restrict__ bo,
                                              const float* __restrict__ src,
                                              const float* __restrict__ g1,
                                              const float* __restrict__ b1g,
                                              const unsigned short* __restrict__ W1f,
                                              const float* __restrict__ b1v,
                                              const unsigned short* __restrict__ W2f,
                                              const float* __restrict__ b2v_,
                                              const float* __restrict__ g2,
                                              const float* __restrict__ b2g,
                                              float* __restrict__ outp) {
  __shared__ char smem[81920];                         // 80 KB exactly
  unsigned short* Xls = (unsigned short*)smem;         // 32 x 256 bf16, swizzled (16 KB)
  unsigned short* Hls = (unsigned short*)(smem + 16384); // 32 x 1024 bf16, swizzled (64 KB)
  float* rsum = (float*)(smem + 16384);                // [32][4], aliases Hls head
  float* rssq = rsum + 128;

  const int t = threadIdx.x;
  const int w = t >> 6, lane = t & 63;
  const int lr = lane & 15, lgrp = lane >> 4;
  const long row0 = (long)blockIdx.x * 32;

  // ---- phase 1: outproj (A-frags direct from global src2bf) ----
  short8 af[2][8];
#pragma unroll
  for (int mt = 0; mt < 2; ++mt)
#pragma unroll
    for (int kt = 0; kt < 8; ++kt)
      af[mt][kt] = *reinterpret_cast<const short8*>(
          &src2bf[(row0 + mt * 16 + lr) * DD + kt * 32 + lgrp * 8]);

  f32x4 acc[2][4];
#pragma unroll
  for (int mt = 0; mt < 2; ++mt)
#pragma unroll
    for (int n = 0; n < 4; ++n) acc[mt][n] = (f32x4){0.f, 0.f, 0.f, 0.f};
#pragma unroll
  for (int n = 0; n < 4; ++n) {
    const int nt = w * 4 + n;
#pragma unroll
    for (int kt = 0; kt < 8; ++kt) {
      const short8 bf_ = *reinterpret_cast<const short8*>(&Wof[((nt * 8 + kt) * 64 + lane) * 8]);
#pragma unroll
      for (int mt = 0; mt < 2; ++mt)
        acc[mt][n] = __builtin_amdgcn_mfma_f32_16x16x32_bf16(af[mt][kt], bf_, acc[mt][n], 0, 0, 0);
    }
  }
  // ---- LN1: residual + reduce; x -> Xls (bf16, swizzled) ----
  {
    float bc[4], gc[4], bgc[4];
#pragma unroll
    for (int n = 0; n < 4; ++n) {
      const int col = w * 64 + n * 16 + lr;
      bc[n] = bo[col]; gc[n] = g1[col]; bgc[n] = b1g[col];
    }
    float vals[2][4][4];
#pragma unroll
    for (int mt = 0; mt < 2; ++mt)
#pragma unroll
      for (int j = 0; j < 4; ++j) {
        const int row = mt * 16 + lgrp * 4 + j;
        float s = 0.f, ss = 0.f;
#pragma unroll
        for (int n = 0; n < 4; ++n) {
          const int col = w * 64 + n * 16 + lr;
          const float v = acc[mt][n][j] + bc[n] + src[(row0 + row) * DD + col];
          vals[mt][n][j] = v;
          s += v; ss += v * v;
        }
#pragma unroll
        for (int m = 1; m <= 8; m <<= 1) { s += __shfl_xor(s, m, 64); ss += __shfl_xor(ss, m, 64); }
        if (lr == 0) { rsum[row * 4 + w] = s; rssq[row * 4 + w] = ss; }
      }
    __syncthreads();
#pragma unroll
    for (int mt = 0; mt < 2; ++mt)
#pragma unroll
      for (int j = 0; j < 4; ++j) {
        const int row = mt * 16 + lgrp * 4 + j;
        const float s  = rsum[row * 4 + 0] + rsum[row * 4 + 1] + rsum[row * 4 + 2] + rsum[row * 4 + 3];
        const float ss = rssq[row * 4 + 0] + rssq[row * 4 + 1] + rssq[row * 4 + 2] + rssq[row * 4 + 3];
        const float mean = s * (1.f / 256.f);
        const float inv  = rsqrtf(ss * (1.f / 256.f) - mean * mean + 1e-5f);
#pragma unroll
        for (int n = 0; n < 4; ++n) {
          const int col = w * 64 + n * 16 + lr;
          const float xv = (vals[mt][n][j] - mean) * inv * gc[n] + bgc[n];
          int byte = row * 512 + col * 2;
          byte ^= (row & 7) << 4;
          *reinterpret_cast<unsigned short*>(reinterpret_cast<char*>(Xls) + byte) = f2bf(xv);
        }
      }
  }
  __syncthreads();   // x ready; LN1 scratch (Hls head) dead -> Hls writable

  // ---- phase 2: FFN1. wave w owns hdims [w*256, w*256+256), 2 half-passes ----
#pragma unroll
  for (int hp = 0; hp < 2; ++hp) {
    f32x4 a2[8][2];
#pragma unroll
    for (int mm = 0; mm < 8; ++mm)
#pragma unroll
      for (int n = 0; n < 2; ++n) a2[mm][n] = (f32x4){0.f, 0.f, 0.f, 0.f};
#pragma unroll
    for (int kt = 0; kt < 8; ++kt) {
      short8 bx[2];
#pragma unroll
      for (int n = 0; n < 2; ++n) {
        const int row = n * 16 + lr;
        int byte = row * 512 + kt * 64 + lgrp * 16;
        byte ^= (row & 7) << 4;
        bx[n] = *reinterpret_cast<const short8*>(reinterpret_cast<const char*>(Xls) + byte);
      }
#pragma unroll
      for (int mm = 0; mm < 8; ++mm) {
        const int ntg = w * 16 + hp * 8 + mm;   // hd tile 0..63
        const short8 aw1 = *reinterpret_cast<const short8*>(&W1f[((ntg * 8 + kt) * 64 + lane) * 8]);
#pragma unroll
        for (int n = 0; n < 2; ++n)
          a2[mm][n] = __builtin_amdgcn_mfma_f32_16x16x32_bf16(aw1, bx[n], a2[mm][n], 0, 0, 0);
      }
    }
    // bias + relu -> Hls [tok][hd] (swizzled, packed 8B)
#pragma unroll
    for (int mm = 0; mm < 8; ++mm) {
      const int ht = w * 16 + hp * 8 + mm;
      const float4 bq = *reinterpret_cast<const float4*>(&b1v[ht * 16 + lgrp * 4]);
#pragma unroll
      for (int n = 0; n < 2; ++n) {
        const int tok = n * 16 + lr;
        int2 pk;
        pk.x = (int)pack2bf(fmaxf(a2[mm][n][0] + bq.x, 0.f),
                            fmaxf(a2[mm][n][1] + bq.y, 0.f));
        pk.y = (int)pack2bf(fmaxf(a2[mm][n][2] + bq.z, 0.f),
                            fmaxf(a2[mm][n][3] + bq.w, 0.f));
        int byte = tok * 2048 + (ht * 16 + lgrp * 4) * 2;
        byte ^= (tok & 7) << 4;
        *reinterpret_cast<int2*>(reinterpret_cast<char*>(Hls) + byte) = pk;
      }
    }
  }
  __syncthreads();   // all h ready

  // ---- phase 3: FFN2. wave w owns cols [w*64, w*64+64) ----
  f32x4 c2[2][4];
#pragma unroll
  for (int mt = 0; mt < 2; ++mt)
#pragma unroll
    for (int n = 0; n < 4; ++n) c2[mt][n] = (f32x4){0.f, 0.f, 0.f, 0.f};
#pragma unroll 4
  for (int kt = 0; kt < 32; ++kt) {
    short8 ha[2];
#pragma unroll
    for (int mt = 0; mt < 2; ++mt) {
      const int row = mt * 16 + lr;
      int byte = row * 2048 + kt * 64 + lgrp * 16;
      byte ^= (row & 7) << 4;
      ha[mt] = *reinterpret_cast<const short8*>(reinterpret_cast<const char*>(Hls) + byte);
    }
#pragma unroll
    for (int n = 0; n < 4; ++n) {
      const int nt = w * 4 + n;
      const short8 bf_ = *reinterpret_cast<const short8*>(&W2f[((nt * 32 + kt) * 64 + lane) * 8]);
#pragma unroll
      for (int mt = 0; mt < 2; ++mt)
        c2[mt][n] = __builtin_amdgcn_mfma_f32_16x16x32_bf16(ha[mt], bf_, c2[mt][n], 0, 0, 0);
    }
  }

  // ---- LN2 epilogue (residual x from Xls; scratch re-aliases Hls head) ----
  float b2c[4], g2c[4], bgc2[4];
#pragma unroll
  for (int n = 0; n < 4; ++n) {
    const int col = w * 64 + n * 16 + lr;
    b2c[n] = b2v_[col]; g2c[n] = g2[col]; bgc2[n] = b2g[col];
  }
  float vals2[2][4][4];
  float sP[2][4], ssP[2][4];
#pragma unroll
  for (int mt = 0; mt < 2; ++mt)
#pragma unroll
    for (int j = 0; j < 4; ++j) {
      const int row = mt * 16 + lgrp * 4 + j;
      float s = 0.f, ss = 0.f;
#pragma unroll
      for (int n = 0; n < 4; ++n) {
        const int col = w * 64 + n * 16 + lr;
        int byte = row * 512 + col * 2;
        byte ^= (row & 7) << 4;
        const float xv = bf2f(*reinterpret_cast<const unsigned short*>(
            reinterpret_cast<const char*>(Xls) + byte));
        const float v = c2[mt][n][j] + b2c[n] + xv;
        vals2[mt][n][j] = v;
        s += v; ss += v * v;
      }
#pragma unroll
      for (int m = 1; m <= 8; m <<= 1) { s += __shfl_xor(s, m, 64); ss += __shfl_xor(ss, m, 64); }
      sP[mt][j] = s; ssP[mt][j] = ss;
    }
  __syncthreads();   // everyone done reading Hls -> scratch writable
#pragma unroll
  for (int mt = 0; mt < 2; ++mt)
#pragma unroll
    for (int j = 0; j < 4; ++j) {
      const int row = mt * 16 + lgrp * 4 + j;
      if (lr == 0) { rsum[row * 4 + w] = sP[mt][j]; rssq[row * 4 + w] = ssP[mt][j]; }
    }
  __syncthreads();
#pragma unroll
  for (int mt = 0; mt < 2; ++mt)
#pragma unroll
    for (int j = 0; j < 4; ++j) {
      const int row = mt * 16 + lgrp * 4 + j;
      const float s  = rsum[row * 4 + 0] + rsum[row * 4 + 1] + rsum[row * 4 + 2] + rsum[row * 4 + 3];
      const float ss = rssq[row * 4 + 0] + rssq[row * 4 + 1] + rssq[row * 4 + 2] + rssq[row * 4 + 3];
      const float mean = s * (1.f / 256.f);
      const float inv  = rsqrtf(ss * (1.f / 256.f) - mean * mean + 1e-5f);
#pragma unroll
      for (int n = 0; n < 4; ++n) {
        const int col = w * 64 + n * 16 + lr;
        outp[(row0 + row) * DD + col] = (vals2[mt][n][j] - mean) * inv * g2c[n] + bgc2[n];
      }
    }
}

extern "C" void kernel_launch(void* const* d_in, const int* in_sizes, int n_in,
                              void* d_out, int out_size, void* d_ws, size_t ws_size,
                              hipStream_t stream) {
  const float* src  = (const float*)d_in[0];
  const float* refp = (const float*)d_in[1];
  const float* pos  = (const float*)d_in[5];
  const float* Wv   = (const float*)d_in[6];
  const float* bv   = (const float*)d_in[7];
  const float* Woff = (const float*)d_in[8];
  const float* boff = (const float*)d_in[9];
  const float* Wat  = (const float*)d_in[10];
  const float* bat  = (const float*)d_in[11];
  const float* Wo   = (const float*)d_in[12];
  const float* bo   = (const float*)d_in[13];
  const float* g1   = (const float*)d_in[14];
  const float* b1g  = (const float*)d_in[15];
  const float* W1   = (const float*)d_in[16];
  const float* b1f  = (const float*)d_in[17];
  const float* W2   = (const float*)d_in[18];
  const float* b2f  = (const float*)d_in[19];
  const float* g2   = (const float*)d_in[20];
  const float* b2g  = (const float*)d_in[21];
  float* out = (float*)d_out;

  // workspace (~46 MB): no xbf, no hfrag
  unsigned short* valh   = (unsigned short*)d_ws;       // NTOK*256 u16 (fp16)
  unsigned short* offbf  = valh + NTOK * 256;           // NTOK*256 u16
  float*          attn   = (float*)(offbf + NTOK * 256);// NTOK*128 f32
  unsigned short* src2bf = (unsigned short*)(attn + NTOK * 128); // NTOK*256 u16
  unsigned short* W1f = src2bf + NTOK * 256;            // 262144
  unsigned short* W2f = W1f + 262144;                   // 262144
  unsigned short* Wvf = W2f + 262144;                   // 65536
  unsigned short* Wqf = Wvf + 65536;                    // 98304
  unsigned short* Wof = Wqf + 98304;                    // 65536

  hipLaunchKernelGGL(k_prep_all, dim3(2944), dim3(256), 0, stream,
                     W1, W2, Wv, Woff, Wat, Wo, W1f, W2f, Wvf, Wqf, Wof);
  hipLaunchKernelGGL(k_vq2, dim3((int)(NTOK / 32)), dim3(256), 0, stream,
                     src, pos, Wvf, bv, Wqf, boff, bat, valh, offbf, attn);
  hipLaunchKernelGGL(k_sample6, dim3((int)(NTOK / 8)), dim3(256), 0, stream,
                     valh, offbf, attn, refp, src2bf);
  hipLaunchKernelGGL(k_tail, dim3((int)(NTOK / 32)), dim3(256), 0, stream,
                     src2bf, Wof, bo, src, g1, b1g, W1f, b1f, W2f, b2f, g2, b2g, out);
}

// Round 15
// 173.605 us; speedup vs baseline: 1.1256x; 1.1256x over previous
//
#include <hip/hip_runtime.h>
#include <hip/hip_fp16.h>

// Problem constants (fixed by setup_inputs)
constexpr int NB   = 4;
constexpr int SLEN = 5440;           // 64*64 + 32*32 + 16*16 + 8*8
constexpr long NTOK = (long)NB * SLEN; // 21760
constexpr int DD   = 256;
constexpr int NH   = 8;
constexpr int DHD  = 32;
constexpr int NL   = 4;
constexpr int NP   = 4;
constexpr int DFF  = 1024;

typedef __attribute__((ext_vector_type(8))) short short8;   // 8 x bf16
typedef __attribute__((ext_vector_type(8))) unsigned short ushort8;
typedef __attribute__((ext_vector_type(4))) float f32x4;
typedef __attribute__((ext_vector_type(2))) int v2i;

static __device__ __forceinline__ unsigned short f2bf(float x) {
  union { float f; unsigned int u; } v; v.f = x;
  unsigned int r = v.u + 0x7fffu + ((v.u >> 16) & 1u);   // RNE
  return (unsigned short)(r >> 16);
}
static __device__ __forceinline__ float bf2f(unsigned short u) {
  union { unsigned int i; float f; } v; v.i = ((unsigned int)u) << 16; return v.f;
}
static __device__ __forceinline__ unsigned int pack2bf(float lo, float hi) {
  return (unsigned int)f2bf(lo) | ((unsigned int)f2bf(hi) << 16);
}
static __device__ __forceinline__ unsigned int pack2h_dup(float a) {
  const unsigned int h = (unsigned int)__half_as_ushort(__float2half(a));
  return h | (h << 16);
}
static __device__ __forceinline__ __half2 u2h2(unsigned int u) {
  union { unsigned int i; __half2 h; } c; c.i = u; return c.h;
}

// B-fragment position for mfma_f32_16x16x32_bf16, weight K x N row-major.
// Dual-use: read as A-fragment it represents W^T (swapped-operand MFMA).
static __device__ __forceinline__ long fragpos(int k, int n, int KT) {
  const int kt = k >> 5, i = k & 7;
  const int lane = ((k >> 3) & 3) * 16 + (n & 15);
  const int nt = n >> 4;
  return (((long)(nt * KT + kt) * 64 + lane) * 8 + i);
}

// ---------------------------------------------------------------------------
// K_prep_all: fragment W1, W2, Wv, [Woff|Wattn], Wo into bf16 MFMA layout.
// ---------------------------------------------------------------------------
__global__ __launch_bounds__(256) void k_prep_all(const float* __restrict__ W1,
                                                  const float* __restrict__ W2,
                                                  const float* __restrict__ Wv,
                                                  const float* __restrict__ Woff,
                                                  const float* __restrict__ Wattn,
                                                  const float* __restrict__ Wo,
                                                  unsigned short* __restrict__ W1f,
                                                  unsigned short* __restrict__ W2f,
                                                  unsigned short* __restrict__ Wvf,
                                                  unsigned short* __restrict__ Wqf,
                                                  unsigned short* __restrict__ Wof) {
  const int g = blockIdx.x * 256 + threadIdx.x;
  if (g < 262144) {                       // W1: 256 x 1024, KT=8
    const int k = g >> 10, n = g & 1023;
    W1f[fragpos(k, n, 8)] = f2bf(W1[g]);
  } else if (g < 524288) {                // W2: 1024 x 256, KT=32
    const int g2 = g - 262144;
    const int k = g2 >> 8, n = g2 & 255;
    W2f[fragpos(k, n, 32)] = f2bf(W2[g2]);
  } else if (g < 589824) {                // Wv: 256 x 256, KT=8
    const int g2 = g - 524288;
    const int k = g2 >> 8, n = g2 & 255;
    Wvf[fragpos(k, n, 8)] = f2bf(Wv[g2]);
  } else if (g < 688128) {                // Wq fused: 256 x 384
    const int g2 = g - 589824;
    const int k = g2 / 384, n = g2 % 384;
    const float w = (n < 256) ? Woff[k * 256 + n] : Wattn[k * 128 + (n - 256)];
    Wqf[fragpos(k, n, 8)] = f2bf(w);
  } else if (g < 753664) {                // Wo: 256 x 256
    const int g2 = g - 688128;
    const int k = g2 >> 8, n = g2 & 255;
    Wof[fragpos(k, n, 8)] = f2bf(Wo[g2]);
  }
}

// ---------------------------------------------------------------------------
// K1+K2 fused (R13-proven): single 16KB LDS buffer.
// ---------------------------------------------------------------------------
__global__ __launch_bounds__(256) void k_vq2(const float* __restrict__ src,
                                             const float* __restrict__ pos,
                                             const unsigned short* __restrict__ Wvf,
                                             const float* __restrict__ bv,
                                             const unsigned short* __restrict__ Wqf,
                                             const float* __restrict__ boff,
                                             const float* __restrict__ battn,
                                             unsigned short* __restrict__ valh,
                                             unsigned short* __restrict__ offbf,
                                             float* __restrict__ attn) {
  __shared__ unsigned short Xs[32 * 256];   // 16 KB
  const int t = threadIdx.x;
  const int w = t >> 6, lane = t & 63;
  const int lr = lane & 15, lgrp = lane >> 4;
  const long row0 = (long)blockIdx.x * 32;
  const int r = t >> 3;
  const int c0 = (t & 7) * 32;

  {
    const float* sp = &src[(row0 + r) * DD + c0];
#pragma unroll
    for (int j = 0; j < 4; ++j) {
      const float4 a = *reinterpret_cast<const float4*>(&sp[j * 8 + 0]);
      const float4 b = *reinterpret_cast<const float4*>(&sp[j * 8 + 4]);
      short8 pk;
      pk[0] = (short)f2bf(a.x); pk[1] = (short)f2bf(a.y);
      pk[2] = (short)f2bf(a.z); pk[3] = (short)f2bf(a.w);
      pk[4] = (short)f2bf(b.x); pk[5] = (short)f2bf(b.y);
      pk[6] = (short)f2bf(b.z); pk[7] = (short)f2bf(b.w);
      int byte = r * 512 + (c0 + j * 8) * 2;
      byte ^= (r & 7) << 4;
      *reinterpret_cast<short8*>(reinterpret_cast<char*>(Xs) + byte) = pk;
    }
  }
  __syncthreads();

  short8 af[2][8];
#pragma unroll
  for (int mt = 0; mt < 2; ++mt)
#pragma unroll
    for (int kt = 0; kt < 8; ++kt) {
      const int row = mt * 16 + lr;
      int byte = row * 512 + kt * 64 + lgrp * 16;
      byte ^= (row & 7) << 4;
      af[mt][kt] = *reinterpret_cast<const short8*>(reinterpret_cast<const char*>(Xs) + byte);
    }

  // ---- phase V ----
  {
    f32x4 acc[2][4];
#pragma unroll
    for (int mt = 0; mt < 2; ++mt)
#pragma unroll
      for (int n = 0; n < 4; ++n) acc[mt][n] = (f32x4){0.f, 0.f, 0.f, 0.f};
#pragma unroll
    for (int n = 0; n < 4; ++n) {
      const int nt = w * 4 + n;
#pragma unroll
      for (int kt = 0; kt < 8; ++kt) {
        const short8 bf_ = *reinterpret_cast<const short8*>(&Wvf[((nt * 8 + kt) * 64 + lane) * 8]);
#pragma unroll
        for (int mt = 0; mt < 2; ++mt)
          acc[mt][n] = __builtin_amdgcn_mfma_f32_16x16x32_bf16(af[mt][kt], bf_, acc[mt][n], 0, 0, 0);
      }
    }
#pragma unroll
    for (int n = 0; n < 4; ++n) {
      const int col = w * 64 + n * 16 + lr;
      const float bb = bv[col];
#pragma unroll
      for (int mt = 0; mt < 2; ++mt)
#pragma unroll
        for (int j = 0; j < 4; ++j) {
          const int row = mt * 16 + lgrp * 4 + j;
          valh[(row0 + row) * DD + col] =
              __half_as_ushort(__float2half(acc[mt][n][j] + bb));
        }
    }
  }
  __syncthreads();

  // in-place Xs += pos
  {
    const float* pp = &pos[(row0 + r) * DD + c0];
#pragma unroll
    for (int j = 0; j < 4; ++j) {
      const float4 c = *reinterpret_cast<const float4*>(&pp[j * 8 + 0]);
      const float4 d = *reinterpret_cast<const float4*>(&pp[j * 8 + 4]);
      int byte = r * 512 + (c0 + j * 8) * 2;
      byte ^= (r & 7) << 4;
      short8 pk = *reinterpret_cast<const short8*>(reinterpret_cast<const char*>(Xs) + byte);
      pk[0] = (short)f2bf(bf2f((unsigned short)pk[0]) + c.x);
      pk[1] = (short)f2bf(bf2f((unsigned short)pk[1]) + c.y);
      pk[2] = (short)f2bf(bf2f((unsigned short)pk[2]) + c.z);
      pk[3] = (short)f2bf(bf2f((unsigned short)pk[3]) + c.w);
      pk[4] = (short)f2bf(bf2f((unsigned short)pk[4]) + d.x);
      pk[5] = (short)f2bf(bf2f((unsigned short)pk[5]) + d.y);
      pk[6] = (short)f2bf(bf2f((unsigned short)pk[6]) + d.z);
      pk[7] = (short)f2bf(bf2f((unsigned short)pk[7]) + d.w);
      *reinterpret_cast<short8*>(reinterpret_cast<char*>(Xs) + byte) = pk;
    }
  }
  __syncthreads();

#pragma unroll
  for (int mt = 0; mt < 2; ++mt)
#pragma unroll
    for (int kt = 0; kt < 8; ++kt) {
      const int row = mt * 16 + lr;
      int byte = row * 512 + kt * 64 + lgrp * 16;
      byte ^= (row & 7) << 4;
      af[mt][kt] = *reinterpret_cast<const short8*>(reinterpret_cast<const char*>(Xs) + byte);
    }

  // ---- phase Q ----
  {
    f32x4 acc[2][6];
#pragma unroll
    for (int mt = 0; mt < 2; ++mt)
#pragma unroll
      for (int i = 0; i < 6; ++i) acc[mt][i] = (f32x4){0.f, 0.f, 0.f, 0.f};
#pragma unroll
    for (int i = 0; i < 6; ++i) {
      const int ntg = w * 6 + i;
#pragma unroll
      for (int kt = 0; kt < 8; ++kt) {
        const short8 bf_ = *reinterpret_cast<const short8*>(&Wqf[((ntg * 8 + kt) * 64 + lane) * 8]);
#pragma unroll
        for (int mt = 0; mt < 2; ++mt)
          acc[mt][i] = __builtin_amdgcn_mfma_f32_16x16x32_bf16(af[mt][kt], bf_, acc[mt][i], 0, 0, 0);
      }
    }
#pragma unroll
    for (int i = 0; i < 6; ++i) {
      const int ntg = w * 6 + i;
      if (ntg < 16) {
        const int col = ntg * 16 + lr;
        const float bb = boff[col];
#pragma unroll
        for (int mt = 0; mt < 2; ++mt)
#pragma unroll
          for (int j = 0; j < 4; ++j) {
            const int row = mt * 16 + lgrp * 4 + j;
            offbf[(row0 + row) * 256 + col] = f2bf(acc[mt][i][j] + bb);
          }
      } else {
        const int na = ntg - 16;       // head index
        const float bb = battn[na * 16 + lr];
#pragma unroll
        for (int mt = 0; mt < 2; ++mt)
#pragma unroll
          for (int j = 0; j < 4; ++j) {
            const int row = mt * 16 + lgrp * 4 + j;
            const float v = acc[mt][i][j] + bb;
            float m = v;
#pragma unroll
            for (int d_ = 1; d_ <= 8; d_ <<= 1) m = fmaxf(m, __shfl_xor(m, d_, 16));
            const float e = __expf(v - m);
            float s = e;
#pragma unroll
            for (int d_ = 1; d_ <= 8; d_ <<= 1) s += __shfl_xor(s, d_, 16);
            attn[(row0 + row) * 128 + na * 16 + lr] = e / s;
          }
      }
    }
  }
}

// ---------------------------------------------------------------------------
// K3: deformable sampling v7 (R12-proven). FP16 value -> pure v_pk_fma_f16.
// ---------------------------------------------------------------------------
__global__ __launch_bounds__(256) void k_sample6(const unsigned short* __restrict__ valh,
                                                 const unsigned short* __restrict__ offbf,
                                                 const float* __restrict__ attn,
                                                 const float* __restrict__ refp,
                                                 unsigned short* __restrict__ src2bf) {
  __shared__ int4  sIdx[4][2][8][16];   // 16 KB
  __shared__ uint4 sWgt[4][2][8][16];   // 16 KB (4 x dup-half2)
  const int t = threadIdx.x;
  const int w = t >> 6, lane = t & 63;
  const int tok = lane >> 5, hg = (lane >> 2) & 7, li = lane & 3;
  const int B = blockIdx.x;
  const int bimg = (B & 7) >> 1;
  const int ii = ((B >> 3) << 1) + (B & 1);       // 0..679
  const long n = (long)bimg * SLEN + ii * 8 + w * 2 + tok;
  const long bOff = (long)bimg * SLEN;

  const int   WlA[4] = {64, 32, 16, 8};
  const float rWA[4] = {1.f / 64.f, 1.f / 32.f, 1.f / 16.f, 1.f / 8.f};
  const int   stA[4] = {0, 4096, 5120, 5376};

#pragma unroll
  for (int q = 0; q < 4; ++q) {       // level = q, point-in-level = li
    const int pt = q * 4 + li;
    const int Wi = WlA[q];
    const float Wf = (float)Wi, rW = rWA[q];
    const float rx = refp[(n * 4 + q) * 2 + 0];
    const float ry = refp[(n * 4 + q) * 2 + 1];
    const float aw = attn[n * 128 + hg * 16 + pt];
    const int oi = ((hg * 4 + q) * 4 + li) * 2;
    const unsigned int opk = *reinterpret_cast<const unsigned int*>(&offbf[n * 256 + oi]);
    const float ox = bf2f((unsigned short)(opk & 0xffff));
    const float oy = bf2f((unsigned short)(opk >> 16));
    const float px = (rx + ox * rW) * Wf - 0.5f;
    const float py = (ry + oy * rW) * Wf - 0.5f;
    const float x0f = floorf(px), y0f = floorf(py);
    const float fx = px - x0f, fy = py - y0f;
    const int x0 = (int)x0f, y0 = (int)y0f;
    int   ic[4];
    float wc[4];
#pragma unroll
    for (int c = 0; c < 4; ++c) {
      const int dx = c & 1, dy = c >> 1;
      const int xi = x0 + dx, yi = y0 + dy;
      const float cw = (dx ? fx : 1.f - fx) * (dy ? fy : 1.f - fy);
      const bool valid = (xi >= 0) && (xi < Wi) && (yi >= 0) && (yi < Wi);
      const int xc = min(max(xi, 0), Wi - 1);
      const int yc = min(max(yi, 0), Wi - 1);
      const long flat = stA[q] + yc * Wi + xc;
      ic[c] = (int)((bOff + flat) * DD + hg * DHD);
      wc[c] = aw * cw * (valid ? 1.f : 0.f);
    }
    const int slot = pt ^ hg;
    sIdx[w][tok][hg][slot] = make_int4(ic[0], ic[1], ic[2], ic[3]);
    sWgt[w][tok][hg][slot] = make_uint4(pack2h_dup(wc[0]), pack2h_dup(wc[1]),
                                        pack2h_dup(wc[2]), pack2h_dup(wc[3]));
  }
  __syncthreads();

  __half2 acc[4];
#pragma unroll
  for (int d = 0; d < 4; ++d) acc[d] = __float2half2_rn(0.f);
#pragma unroll 4
  for (int pt = 0; pt < 16; ++pt) {
    const int slot = pt ^ hg;
    const int4  ia = sIdx[w][tok][hg][slot];
    const uint4 wp = sWgt[w][tok][hg][slot];
    const uint4 u0 = *reinterpret_cast<const uint4*>(&valh[(long)ia.x + li * 8]);
    const uint4 u1 = *reinterpret_cast<const uint4*>(&valh[(long)ia.y + li * 8]);
    const uint4 u2 = *reinterpret_cast<const uint4*>(&valh[(long)ia.z + li * 8]);
    const uint4 u3 = *reinterpret_cast<const uint4*>(&valh[(long)ia.w + li * 8]);
    const __half2 w0 = u2h2(wp.x), w1 = u2h2(wp.y), w2 = u2h2(wp.z), w3 = u2h2(wp.w);
    acc[0] = __hfma2(u2h2(u0.x), w0, acc[0]);
    acc[1] = __hfma2(u2h2(u0.y), w0, acc[1]);
    acc[2] = __hfma2(u2h2(u0.z), w0, acc[2]);
    acc[3] = __hfma2(u2h2(u0.w), w0, acc[3]);
    acc[0] = __hfma2(u2h2(u1.x), w1, acc[0]);
    acc[1] = __hfma2(u2h2(u1.y), w1, acc[1]);
    acc[2] = __hfma2(u2h2(u1.z), w1, acc[2]);
    acc[3] = __hfma2(u2h2(u1.w), w1, acc[3]);
    acc[0] = __hfma2(u2h2(u2.x), w2, acc[0]);
    acc[1] = __hfma2(u2h2(u2.y), w2, acc[1]);
    acc[2] = __hfma2(u2h2(u2.z), w2, acc[2]);
    acc[3] = __hfma2(u2h2(u2.w), w2, acc[3]);
    acc[0] = __hfma2(u2h2(u3.x), w3, acc[0]);
    acc[1] = __hfma2(u2h2(u3.y), w3, acc[1]);
    acc[2] = __hfma2(u2h2(u3.z), w3, acc[2]);
    acc[3] = __hfma2(u2h2(u3.w), w3, acc[3]);
  }
  ushort8 o;
#pragma unroll
  for (int d = 0; d < 4; ++d) {
    o[2 * d]     = f2bf(__half2float(__low2half(acc[d])));
    o[2 * d + 1] = f2bf(__half2float(__high2half(acc[d])));
  }
  *reinterpret_cast<ushort8*>(&src2bf[n * DD + hg * DHD + li * 8]) = o;
}

// ---------------------------------------------------------------------------
// K4: xbf = bf16(LN1(src + src2bf @ W_out + b_out)). (R8-proven, 32-row)
// ---------------------------------------------------------------------------
__global__ __launch_bounds__(256) void k_outproj_mfma(const unsigned short* __restrict__ src2bf,
                                                      const unsigned short* __restrict__ Wof,
                                                      const float* __restrict__ bo,
                                                      const float* __restrict__ src,
                                                      const float* __restrict__ g1,
                                                      const float* __restrict__ b1g,
                                                      unsigned short* __restrict__ xbf) {
  __shared__ float rsum[32][4];
  __shared__ float rssq[32][4];
  const int t = threadIdx.x;
  const int w = t >> 6, lane = t & 63;
  const int lr = lane & 15, lgrp = lane >> 4;
  const long row0 = (long)blockIdx.x * 32;

  short8 af[2][8];
#pragma unroll
  for (int mt = 0; mt < 2; ++mt)
#pragma unroll
    for (int kt = 0; kt < 8; ++kt)
      af[mt][kt] = *reinterpret_cast<const short8*>(
          &src2bf[(row0 + mt * 16 + lr) * DD + kt * 32 + lgrp * 8]);

  f32x4 acc[2][4];
#pragma unroll
  for (int mt = 0; mt < 2; ++mt)
#pragma unroll
    for (int n = 0; n < 4; ++n) acc[mt][n] = (f32x4){0.f, 0.f, 0.f, 0.f};
#pragma unroll
  for (int n = 0; n < 4; ++n) {
    const int nt = w * 4 + n;
#pragma unroll
    for (int kt = 0; kt < 8; ++kt) {
      const short8 bf_ = *reinterpret_cast<const short8*>(&Wof[((nt * 8 + kt) * 64 + lane) * 8]);
#pragma unroll
      for (int mt = 0; mt < 2; ++mt)
        acc[mt][n] = __builtin_amdgcn_mfma_f32_16x16x32_bf16(af[mt][kt], bf_, acc[mt][n], 0, 0, 0);
    }
  }
  float bc[4], gc[4], bgc[4];
#pragma unroll
  for (int n = 0; n < 4; ++n) {
    const int col = w * 64 + n * 16 + lr;
    bc[n] = bo[col]; gc[n] = g1[col]; bgc[n] = b1g[col];
  }
  float vals[2][4][4];
#pragma unroll
  for (int mt = 0; mt < 2; ++mt)
#pragma unroll
    for (int j = 0; j < 4; ++j) {
      const int row = mt * 16 + lgrp * 4 + j;
      float s = 0.f, ss = 0.f;
#pragma unroll
      for (int n = 0; n < 4; ++n) {
        const int col = w * 64 + n * 16 + lr;
        const float v = acc[mt][n][j] + bc[n] + src[(row0 + row) * DD + col];
        vals[mt][n][j] = v;
        s += v; ss += v * v;
      }
#pragma unroll
      for (int m = 1; m <= 8; m <<= 1) { s += __shfl_xor(s, m, 64); ss += __shfl_xor(ss, m, 64); }
      if (lr == 0) { rsum[row][w] = s; rssq[row][w] = ss; }
    }
  __syncthreads();
#pragma unroll
  for (int mt = 0; mt < 2; ++mt)
#pragma unroll
    for (int j = 0; j < 4; ++j) {
      const int row = mt * 16 + lgrp * 4 + j;
      const float s  = rsum[row][0] + rsum[row][1] + rsum[row][2] + rsum[row][3];
      const float ss = rssq[row][0] + rssq[row][1] + rssq[row][2] + rssq[row][3];
      const float mean = s * (1.f / 256.f);
      const float inv  = rsqrtf(ss * (1.f / 256.f) - mean * mean + 1e-5f);
#pragma unroll
      for (int n = 0; n < 4; ++n) {
        const int col = w * 64 + n * 16 + lr;
        xbf[(row0 + row) * DD + col] = f2bf((vals[mt][n][j] - mean) * inv * gc[n] + bgc[n]);
      }
    }
}

// ---------------------------------------------------------------------------
// K5a: H in TILED layout; grid (340, 4) (R13-proven). NEW: non-temporal
// stores for hfrag (write-once stream; keep L2 for xbf/W1f).
// ---------------------------------------------------------------------------
__global__ __launch_bounds__(256) void k_ffn1e(const unsigned short* __restrict__ xbf,
                                               const unsigned short* __restrict__ W1f,
                                               const float* __restrict__ b1v,
                                               unsigned short* __restrict__ hfrag) {
  const int t = threadIdx.x;
  const int w = t >> 6, lane = t & 63;
  const int lr = lane & 15, lgrp = lane >> 4;
  const long row0 = (long)blockIdx.x * 64;
  const int hg = blockIdx.y;                // 256-hdim quarter (0..3)

  f32x4 acc[4][4];                          // [mm=hd tile][n=token tile]
#pragma unroll
  for (int mm = 0; mm < 4; ++mm)
#pragma unroll
    for (int n = 0; n < 4; ++n) acc[mm][n] = (f32x4){0.f, 0.f, 0.f, 0.f};

#pragma unroll
  for (int kt = 0; kt < 8; ++kt) {
    short8 bx[4];
#pragma unroll
    for (int n = 0; n < 4; ++n)
      bx[n] = *reinterpret_cast<const short8*>(
          &xbf[(row0 + n * 16 + lr) * DD + kt * 32 + lgrp * 8]);
#pragma unroll
    for (int mm = 0; mm < 4; ++mm) {
      const int ntg = hg * 16 + w * 4 + mm;
      const short8 aw1 = *reinterpret_cast<const short8*>(&W1f[((ntg * 8 + kt) * 64 + lane) * 8]);
#pragma unroll
      for (int n = 0; n < 4; ++n)
        acc[mm][n] = __builtin_amdgcn_mfma_f32_16x16x32_bf16(aw1, bx[n], acc[mm][n], 0, 0, 0);
    }
  }

#pragma unroll
  for (int mm = 0; mm < 4; ++mm) {
    const int ht = hg * 16 + w * 4 + mm;                      // hd-tile 0..63
    const float4 bq = *reinterpret_cast<const float4*>(&b1v[ht * 16 + lgrp * 4]);
#pragma unroll
    for (int n = 0; n < 4; ++n) {
      const long tt = (long)blockIdx.x * 4 + n;               // token-tile
      const long tbase = (tt * 64 + ht) * 256;
      v2i pk;
      pk[0] = (int)pack2bf(fmaxf(acc[mm][n][0] + bq.x, 0.f),
                           fmaxf(acc[mm][n][1] + bq.y, 0.f));
      pk[1] = (int)pack2bf(fmaxf(acc[mm][n][2] + bq.z, 0.f),
                           fmaxf(acc[mm][n][3] + bq.w, 0.f));
      __builtin_nontemporal_store(pk, reinterpret_cast<v2i*>(&hfrag[tbase + lane * 4]));
    }
  }
}

// ---------------------------------------------------------------------------
// K5b: out = LN2(xbf + H @ W2 + b2). (R10-proven, tiled-H reads). NEW:
// non-temporal hfrag loads (read-once) + non-temporal out stores.
// ---------------------------------------------------------------------------
__global__ __launch_bounds__(256) void k_ffn2t(const unsigned short* __restrict__ hfrag,
                                               const unsigned short* __restrict__ W2f,
                                               const float* __restrict__ b2v_,
                                               const unsigned short* __restrict__ xbf,
                                               const float* __restrict__ g2,
                                               const float* __restrict__ b2g,
                                               float* __restrict__ outp) {
  __shared__ float rsum[32][4];
  __shared__ float rssq[32][4];
  const int t = threadIdx.x;
  const int w = t >> 6, lane = t & 63;
  const int lr = lane & 15, lgrp = lane >> 4;
  const long row0 = (long)blockIdx.x * 32;

  f32x4 acc[2][4];
#pragma unroll
  for (int mt = 0; mt < 2; ++mt)
#pragma unroll
    for (int n = 0; n < 4; ++n) acc[mt][n] = (f32x4){0.f, 0.f, 0.f, 0.f};

#pragma unroll 4
  for (int kt = 0; kt < 32; ++kt) {
    short8 ha[2];
#pragma unroll
    for (int mt = 0; mt < 2; ++mt) {
      const long tt = (row0 >> 4) + mt;
      const long tb = (tt * 64 + kt * 2 + (lgrp >> 1)) * 256;
      const unsigned short* tp = &hfrag[tb + (lgrp & 1) * 128 + lr * 4];
      union { short8 s8; struct { v2i lo, hi; } p; } u;
      u.p.lo = __builtin_nontemporal_load(reinterpret_cast<const v2i*>(tp));        // i 0..3
      u.p.hi = __builtin_nontemporal_load(reinterpret_cast<const v2i*>(tp + 64));   // i 4..7
      ha[mt] = u.s8;
    }
#pragma unroll
    for (int n = 0; n < 4; ++n) {
      const int nt = w * 4 + n;
      const short8 bf_ = *reinterpret_cast<const short8*>(&W2f[((nt * 32 + kt) * 64 + lane) * 8]);
#pragma unroll
      for (int mt = 0; mt < 2; ++mt)
        acc[mt][n] = __builtin_amdgcn_mfma_f32_16x16x32_bf16(ha[mt], bf_, acc[mt][n], 0, 0, 0);
    }
  }

  float b2c[4], g2c[4], bgc[4];
#pragma unroll
  for (int n = 0; n < 4; ++n) {
    const int col = w * 64 + n * 16 + lr;
    b2c[n] = b2v_[col]; g2c[n] = g2[col]; bgc[n] = b2g[col];
  }
  float vals[2][4][4];
#pragma unroll
  for (int mt = 0; mt < 2; ++mt)
#pragma unroll
    for (int j = 0; j < 4; ++j) {
      const int row = mt * 16 + lgrp * 4 + j;
      float s = 0.f, ss = 0.f;
#pragma unroll
      for (int n = 0; n < 4; ++n) {
        const int col = w * 64 + n * 16 + lr;
        const float v = acc[mt][n][j] + b2c[n] + bf2f(xbf[(row0 + row) * DD + col]);
        vals[mt][n][j] = v;
        s += v; ss += v * v;
      }
#pragma unroll
      for (int m = 1; m <= 8; m <<= 1) { s += __shfl_xor(s, m, 64); ss += __shfl_xor(ss, m, 64); }
      if (lr == 0) { rsum[row][w] = s; rssq[row][w] = ss; }
    }
  __syncthreads();
#pragma unroll
  for (int mt = 0; mt < 2; ++mt)
#pragma unroll
    for (int j = 0; j < 4; ++j) {
      const int row = mt * 16 + lgrp * 4 + j;
      const float s  = rsum[row][0] + rsum[row][1] + rsum[row][2] + rsum[row][3];
      const float ss = rssq[row][0] + rssq[row][1] + rssq[row][2] + rssq[row][3];
      const float mean = s * (1.f / 256.f);
      const float inv  = rsqrtf(ss * (1.f / 256.f) - mean * mean + 1e-5f);
#pragma unroll
      for (int n = 0; n < 4; ++n) {
        const int col = w * 64 + n * 16 + lr;
        __builtin_nontemporal_store((vals[mt][n][j] - mean) * inv * g2c[n] + bgc[n],
                                    &outp[(row0 + row) * DD + col]);
      }
    }
}

extern "C" void kernel_launch(void* const* d_in, const int* in_sizes, int n_in,
                              void* d_out, int out_size, void* d_ws, size_t ws_size,
                              hipStream_t stream) {
  const float* src  = (const float*)d_in[0];
  const float* refp = (const float*)d_in[1];
  const float* pos  = (const float*)d_in[5];
  const float* Wv   = (const float*)d_in[6];
  const float* bv   = (const float*)d_in[7];
  const float* Woff = (const float*)d_in[8];
  const float* boff = (const float*)d_in[9];
  const float* Wat  = (const float*)d_in[10];
  const float* bat  = (const float*)d_in[11];
  const float* Wo   = (const float*)d_in[12];
  const float* bo   = (const float*)d_in[13];
  const float* g1   = (const float*)d_in[14];
  const float* b1g  = (const float*)d_in[15];
  const float* W1   = (const float*)d_in[16];
  const float* b1f  = (const float*)d_in[17];
  const float* W2   = (const float*)d_in[18];
  const float* b2f  = (const float*)d_in[19];
  const float* g2   = (const float*)d_in[20];
  const float* b2g  = (const float*)d_in[21];
  float* out = (float*)d_out;

  // workspace layout (R13-proven):
  unsigned short* valh   = (unsigned short*)d_ws;       // NTOK*256 u16 (fp16)
  unsigned short* offbf  = valh + NTOK * 256;           // NTOK*256 u16
  float*          attn   = (float*)(offbf + NTOK * 256);// NTOK*128 f32
  unsigned short* src2bf = (unsigned short*)(attn + NTOK * 128); // NTOK*256 u16
  unsigned short* xbf    = src2bf + NTOK * 256;         // NTOK*256 u16
  unsigned short* W1f = xbf + NTOK * 256;               // 262144
  unsigned short* W2f = W1f + 262144;                   // 262144
  unsigned short* Wvf = W2f + 262144;                   // 65536
  unsigned short* Wqf = Wvf + 65536;                    // 98304
  unsigned short* Wof = Wqf + 98304;                    // 65536
  unsigned short* frag_end = Wof + 65536;
  const size_t used  = (size_t)((char*)frag_end - (char*)d_ws);
  const size_t hneed = (size_t)NTOK * 1024 * 2;
  unsigned short* hfrag = (used + hneed <= ws_size) ? frag_end
                                                    : (unsigned short*)d_ws;

  hipLaunchKernelGGL(k_prep_all, dim3(2944), dim3(256), 0, stream,
                     W1, W2, Wv, Woff, Wat, Wo, W1f, W2f, Wvf, Wqf, Wof);
  hipLaunchKernelGGL(k_vq2, dim3((int)(NTOK / 32)), dim3(256), 0, stream,
                     src, pos, Wvf, bv, Wqf, boff, bat, valh, offbf, attn);
  hipLaunchKernelGGL(k_sample6, dim3((int)(NTOK / 8)), dim3(256), 0, stream,
                     valh, offbf, attn, refp, src2bf);
  hipLaunchKernelGGL(k_outproj_mfma, dim3((int)(NTOK / 32)), dim3(256), 0, stream,
                     src2bf, Wof, bo, src, g1, b1g, xbf);
  hipLaunchKernelGGL(k_ffn1e, dim3((int)(NTOK / 64), 4), dim3(256), 0, stream,
                     xbf, W1f, b1f, hfrag);
  hipLaunchKernelGGL(k_ffn2t, dim3((int)(NTOK / 32)), dim3(256), 0, stream,
                     hfrag, W2f, b2f, xbf, g2, b2g, out);
}

// Round 16
// 159.224 us; speedup vs baseline: 1.2272x; 1.0903x over previous
//
#include <hip/hip_runtime.h>
#include <hip/hip_fp16.h>

// Problem constants (fixed by setup_inputs)
constexpr int NB   = 4;
constexpr int SLEN = 5440;           // 64*64 + 32*32 + 16*16 + 8*8
constexpr long NTOK = (long)NB * SLEN; // 21760
constexpr int DD   = 256;
constexpr int NH   = 8;
constexpr int DHD  = 32;
constexpr int NL   = 4;
constexpr int NP   = 4;
constexpr int DFF  = 1024;

typedef __attribute__((ext_vector_type(8))) short short8;   // 8 x bf16
typedef __attribute__((ext_vector_type(8))) unsigned short ushort8;
typedef __attribute__((ext_vector_type(4))) float f32x4;

static __device__ __forceinline__ unsigned short f2bf(float x) {
  union { float f; unsigned int u; } v; v.f = x;
  unsigned int r = v.u + 0x7fffu + ((v.u >> 16) & 1u);   // RNE
  return (unsigned short)(r >> 16);
}
static __device__ __forceinline__ float bf2f(unsigned short u) {
  union { unsigned int i; float f; } v; v.i = ((unsigned int)u) << 16; return v.f;
}
static __device__ __forceinline__ unsigned int pack2bf(float lo, float hi) {
  return (unsigned int)f2bf(lo) | ((unsigned int)f2bf(hi) << 16);
}
static __device__ __forceinline__ unsigned int pack2h_dup(float a) {
  const unsigned int h = (unsigned int)__half_as_ushort(__float2half(a));
  return h | (h << 16);
}
static __device__ __forceinline__ __half2 u2h2(unsigned int u) {
  union { unsigned int i; __half2 h; } c; c.i = u; return c.h;
}

// B-fragment position for mfma_f32_16x16x32_bf16, weight K x N row-major.
// Dual-use: read as A-fragment it represents W^T (swapped-operand MFMA).
static __device__ __forceinline__ long fragpos(int k, int n, int KT) {
  const int kt = k >> 5, i = k & 7;
  const int lane = ((k >> 3) & 3) * 16 + (n & 15);
  const int nt = n >> 4;
  return (((long)(nt * KT + kt) * 64 + lane) * 8 + i);
}

// ---------------------------------------------------------------------------
// K_prep_all: fragment W1, W2, Wv, [Woff|Wattn], Wo into bf16 MFMA layout.
// ---------------------------------------------------------------------------
__global__ __launch_bounds__(256) void k_prep_all(const float* __restrict__ W1,
                                                  const float* __restrict__ W2,
                                                  const float* __restrict__ Wv,
                                                  const float* __restrict__ Woff,
                                                  const float* __restrict__ Wattn,
                                                  const float* __restrict__ Wo,
                                                  unsigned short* __restrict__ W1f,
                                                  unsigned short* __restrict__ W2f,
                                                  unsigned short* __restrict__ Wvf,
                                                  unsigned short* __restrict__ Wqf,
                                                  unsigned short* __restrict__ Wof) {
  const int g = blockIdx.x * 256 + threadIdx.x;
  if (g < 262144) {                       // W1: 256 x 1024, KT=8
    const int k = g >> 10, n = g & 1023;
    W1f[fragpos(k, n, 8)] = f2bf(W1[g]);
  } else if (g < 524288) {                // W2: 1024 x 256, KT=32
    const int g2 = g - 262144;
    const int k = g2 >> 8, n = g2 & 255;
    W2f[fragpos(k, n, 32)] = f2bf(W2[g2]);
  } else if (g < 589824) {                // Wv: 256 x 256, KT=8
    const int g2 = g - 524288;
    const int k = g2 >> 8, n = g2 & 255;
    Wvf[fragpos(k, n, 8)] = f2bf(Wv[g2]);
  } else if (g < 688128) {                // Wq fused: 256 x 384
    const int g2 = g - 589824;
    const int k = g2 / 384, n = g2 % 384;
    const float w = (n < 256) ? Woff[k * 256 + n] : Wattn[k * 128 + (n - 256)];
    Wqf[fragpos(k, n, 8)] = f2bf(w);
  } else if (g < 753664) {                // Wo: 256 x 256
    const int g2 = g - 688128;
    const int k = g2 >> 8, n = g2 & 255;
    Wof[fragpos(k, n, 8)] = f2bf(Wo[g2]);
  }
}

// ---------------------------------------------------------------------------
// K1+K2 fused (R13-proven): single 16KB LDS buffer.
// ---------------------------------------------------------------------------
__global__ __launch_bounds__(256) void k_vq2(const float* __restrict__ src,
                                             const float* __restrict__ pos,
                                             const unsigned short* __restrict__ Wvf,
                                             const float* __restrict__ bv,
                                             const unsigned short* __restrict__ Wqf,
                                             const float* __restrict__ boff,
                                             const float* __restrict__ battn,
                                             unsigned short* __restrict__ valh,
                                             unsigned short* __restrict__ offbf,
                                             float* __restrict__ attn) {
  __shared__ unsigned short Xs[32 * 256];   // 16 KB
  const int t = threadIdx.x;
  const int w = t >> 6, lane = t & 63;
  const int lr = lane & 15, lgrp = lane >> 4;
  const long row0 = (long)blockIdx.x * 32;
  const int r = t >> 3;
  const int c0 = (t & 7) * 32;

  {
    const float* sp = &src[(row0 + r) * DD + c0];
#pragma unroll
    for (int j = 0; j < 4; ++j) {
      const float4 a = *reinterpret_cast<const float4*>(&sp[j * 8 + 0]);
      const float4 b = *reinterpret_cast<const float4*>(&sp[j * 8 + 4]);
      short8 pk;
      pk[0] = (short)f2bf(a.x); pk[1] = (short)f2bf(a.y);
      pk[2] = (short)f2bf(a.z); pk[3] = (short)f2bf(a.w);
      pk[4] = (short)f2bf(b.x); pk[5] = (short)f2bf(b.y);
      pk[6] = (short)f2bf(b.z); pk[7] = (short)f2bf(b.w);
      int byte = r * 512 + (c0 + j * 8) * 2;
      byte ^= (r & 7) << 4;
      *reinterpret_cast<short8*>(reinterpret_cast<char*>(Xs) + byte) = pk;
    }
  }
  __syncthreads();

  short8 af[2][8];
#pragma unroll
  for (int mt = 0; mt < 2; ++mt)
#pragma unroll
    for (int kt = 0; kt < 8; ++kt) {
      const int row = mt * 16 + lr;
      int byte = row * 512 + kt * 64 + lgrp * 16;
      byte ^= (row & 7) << 4;
      af[mt][kt] = *reinterpret_cast<const short8*>(reinterpret_cast<const char*>(Xs) + byte);
    }

  // ---- phase V ----
  {
    f32x4 acc[2][4];
#pragma unroll
    for (int mt = 0; mt < 2; ++mt)
#pragma unroll
      for (int n = 0; n < 4; ++n) acc[mt][n] = (f32x4){0.f, 0.f, 0.f, 0.f};
#pragma unroll
    for (int n = 0; n < 4; ++n) {
      const int nt = w * 4 + n;
#pragma unroll
      for (int kt = 0; kt < 8; ++kt) {
        const short8 bf_ = *reinterpret_cast<const short8*>(&Wvf[((nt * 8 + kt) * 64 + lane) * 8]);
#pragma unroll
        for (int mt = 0; mt < 2; ++mt)
          acc[mt][n] = __builtin_amdgcn_mfma_f32_16x16x32_bf16(af[mt][kt], bf_, acc[mt][n], 0, 0, 0);
      }
    }
#pragma unroll
    for (int n = 0; n < 4; ++n) {
      const int col = w * 64 + n * 16 + lr;
      const float bb = bv[col];
#pragma unroll
      for (int mt = 0; mt < 2; ++mt)
#pragma unroll
        for (int j = 0; j < 4; ++j) {
          const int row = mt * 16 + lgrp * 4 + j;
          valh[(row0 + row) * DD + col] =
              __half_as_ushort(__float2half(acc[mt][n][j] + bb));
        }
    }
  }
  __syncthreads();

  // in-place Xs += pos
  {
    const float* pp = &pos[(row0 + r) * DD + c0];
#pragma unroll
    for (int j = 0; j < 4; ++j) {
      const float4 c = *reinterpret_cast<const float4*>(&pp[j * 8 + 0]);
      const float4 d = *reinterpret_cast<const float4*>(&pp[j * 8 + 4]);
      int byte = r * 512 + (c0 + j * 8) * 2;
      byte ^= (r & 7) << 4;
      short8 pk = *reinterpret_cast<const short8*>(reinterpret_cast<const char*>(Xs) + byte);
      pk[0] = (short)f2bf(bf2f((unsigned short)pk[0]) + c.x);
      pk[1] = (short)f2bf(bf2f((unsigned short)pk[1]) + c.y);
      pk[2] = (short)f2bf(bf2f((unsigned short)pk[2]) + c.z);
      pk[3] = (short)f2bf(bf2f((unsigned short)pk[3]) + c.w);
      pk[4] = (short)f2bf(bf2f((unsigned short)pk[4]) + d.x);
      pk[5] = (short)f2bf(bf2f((unsigned short)pk[5]) + d.y);
      pk[6] = (short)f2bf(bf2f((unsigned short)pk[6]) + d.z);
      pk[7] = (short)f2bf(bf2f((unsigned short)pk[7]) + d.w);
      *reinterpret_cast<short8*>(reinterpret_cast<char*>(Xs) + byte) = pk;
    }
  }
  __syncthreads();

#pragma unroll
  for (int mt = 0; mt < 2; ++mt)
#pragma unroll
    for (int kt = 0; kt < 8; ++kt) {
      const int row = mt * 16 + lr;
      int byte = row * 512 + kt * 64 + lgrp * 16;
      byte ^= (row & 7) << 4;
      af[mt][kt] = *reinterpret_cast<const short8*>(reinterpret_cast<const char*>(Xs) + byte);
    }

  // ---- phase Q ----
  {
    f32x4 acc[2][6];
#pragma unroll
    for (int mt = 0; mt < 2; ++mt)
#pragma unroll
      for (int i = 0; i < 6; ++i) acc[mt][i] = (f32x4){0.f, 0.f, 0.f, 0.f};
#pragma unroll
    for (int i = 0; i < 6; ++i) {
      const int ntg = w * 6 + i;
#pragma unroll
      for (int kt = 0; kt < 8; ++kt) {
        const short8 bf_ = *reinterpret_cast<const short8*>(&Wqf[((ntg * 8 + kt) * 64 + lane) * 8]);
#pragma unroll
        for (int mt = 0; mt < 2; ++mt)
          acc[mt][i] = __builtin_amdgcn_mfma_f32_16x16x32_bf16(af[mt][kt], bf_, acc[mt][i], 0, 0, 0);
      }
    }
#pragma unroll
    for (int i = 0; i < 6; ++i) {
      const int ntg = w * 6 + i;
      if (ntg < 16) {
        const int col = ntg * 16 + lr;
        const float bb = boff[col];
#pragma unroll
        for (int mt = 0; mt < 2; ++mt)
#pragma unroll
          for (int j = 0; j < 4; ++j) {
            const int row = mt * 16 + lgrp * 4 + j;
            offbf[(row0 + row) * 256 + col] = f2bf(acc[mt][i][j] + bb);
          }
      } else {
        const int na = ntg - 16;       // head index
        const float bb = battn[na * 16 + lr];
#pragma unroll
        for (int mt = 0; mt < 2; ++mt)
#pragma unroll
          for (int j = 0; j < 4; ++j) {
            const int row = mt * 16 + lgrp * 4 + j;
            const float v = acc[mt][i][j] + bb;
            float m = v;
#pragma unroll
            for (int d_ = 1; d_ <= 8; d_ <<= 1) m = fmaxf(m, __shfl_xor(m, d_, 16));
            const float e = __expf(v - m);
            float s = e;
#pragma unroll
            for (int d_ = 1; d_ <= 8; d_ <<= 1) s += __shfl_xor(s, d_, 16);
            attn[(row0 + row) * 128 + na * 16 + lr] = e / s;
          }
      }
    }
  }
}

// ---------------------------------------------------------------------------
// K3: deformable sampling v7 (R12-proven). FP16 value -> pure v_pk_fma_f16.
// ---------------------------------------------------------------------------
__global__ __launch_bounds__(256) void k_sample6(const unsigned short* __restrict__ valh,
                                                 const unsigned short* __restrict__ offbf,
                                                 const float* __restrict__ attn,
                                                 const float* __restrict__ refp,
                                                 unsigned short* __restrict__ src2bf) {
  __shared__ int4  sIdx[4][2][8][16];   // 16 KB
  __shared__ uint4 sWgt[4][2][8][16];   // 16 KB (4 x dup-half2)
  const int t = threadIdx.x;
  const int w = t >> 6, lane = t & 63;
  const int tok = lane >> 5, hg = (lane >> 2) & 7, li = lane & 3;
  const int B = blockIdx.x;
  const int bimg = (B & 7) >> 1;
  const int ii = ((B >> 3) << 1) + (B & 1);       // 0..679
  const long n = (long)bimg * SLEN + ii * 8 + w * 2 + tok;
  const long bOff = (long)bimg * SLEN;

  const int   WlA[4] = {64, 32, 16, 8};
  const float rWA[4] = {1.f / 64.f, 1.f / 32.f, 1.f / 16.f, 1.f / 8.f};
  const int   stA[4] = {0, 4096, 5120, 5376};

#pragma unroll
  for (int q = 0; q < 4; ++q) {       // level = q, point-in-level = li
    const int pt = q * 4 + li;
    const int Wi = WlA[q];
    const float Wf = (float)Wi, rW = rWA[q];
    const float rx = refp[(n * 4 + q) * 2 + 0];
    const float ry = refp[(n * 4 + q) * 2 + 1];
    const float aw = attn[n * 128 + hg * 16 + pt];
    const int oi = ((hg * 4 + q) * 4 + li) * 2;
    const unsigned int opk = *reinterpret_cast<const unsigned int*>(&offbf[n * 256 + oi]);
    const float ox = bf2f((unsigned short)(opk & 0xffff));
    const float oy = bf2f((unsigned short)(opk >> 16));
    const float px = (rx + ox * rW) * Wf - 0.5f;
    const float py = (ry + oy * rW) * Wf - 0.5f;
    const float x0f = floorf(px), y0f = floorf(py);
    const float fx = px - x0f, fy = py - y0f;
    const int x0 = (int)x0f, y0 = (int)y0f;
    int   ic[4];
    float wc[4];
#pragma unroll
    for (int c = 0; c < 4; ++c) {
      const int dx = c & 1, dy = c >> 1;
      const int xi = x0 + dx, yi = y0 + dy;
      const float cw = (dx ? fx : 1.f - fx) * (dy ? fy : 1.f - fy);
      const bool valid = (xi >= 0) && (xi < Wi) && (yi >= 0) && (yi < Wi);
      const int xc = min(max(xi, 0), Wi - 1);
      const int yc = min(max(yi, 0), Wi - 1);
      const long flat = stA[q] + yc * Wi + xc;
      ic[c] = (int)((bOff + flat) * DD + hg * DHD);
      wc[c] = aw * cw * (valid ? 1.f : 0.f);
    }
    const int slot = pt ^ hg;
    sIdx[w][tok][hg][slot] = make_int4(ic[0], ic[1], ic[2], ic[3]);
    sWgt[w][tok][hg][slot] = make_uint4(pack2h_dup(wc[0]), pack2h_dup(wc[1]),
                                        pack2h_dup(wc[2]), pack2h_dup(wc[3]));
  }
  __syncthreads();

  __half2 acc[4];
#pragma unroll
  for (int d = 0; d < 4; ++d) acc[d] = __float2half2_rn(0.f);
#pragma unroll 4
  for (int pt = 0; pt < 16; ++pt) {
    const int slot = pt ^ hg;
    const int4  ia = sIdx[w][tok][hg][slot];
    const uint4 wp = sWgt[w][tok][hg][slot];
    const uint4 u0 = *reinterpret_cast<const uint4*>(&valh[(long)ia.x + li * 8]);
    const uint4 u1 = *reinterpret_cast<const uint4*>(&valh[(long)ia.y + li * 8]);
    const uint4 u2 = *reinterpret_cast<const uint4*>(&valh[(long)ia.z + li * 8]);
    const uint4 u3 = *reinterpret_cast<const uint4*>(&valh[(long)ia.w + li * 8]);
    const __half2 w0 = u2h2(wp.x), w1 = u2h2(wp.y), w2 = u2h2(wp.z), w3 = u2h2(wp.w);
    acc[0] = __hfma2(u2h2(u0.x), w0, acc[0]);
    acc[1] = __hfma2(u2h2(u0.y), w0, acc[1]);
    acc[2] = __hfma2(u2h2(u0.z), w0, acc[2]);
    acc[3] = __hfma2(u2h2(u0.w), w0, acc[3]);
    acc[0] = __hfma2(u2h2(u1.x), w1, acc[0]);
    acc[1] = __hfma2(u2h2(u1.y), w1, acc[1]);
    acc[2] = __hfma2(u2h2(u1.z), w1, acc[2]);
    acc[3] = __hfma2(u2h2(u1.w), w1, acc[3]);
    acc[0] = __hfma2(u2h2(u2.x), w2, acc[0]);
    acc[1] = __hfma2(u2h2(u2.y), w2, acc[1]);
    acc[2] = __hfma2(u2h2(u2.z), w2, acc[2]);
    acc[3] = __hfma2(u2h2(u2.w), w2, acc[3]);
    acc[0] = __hfma2(u2h2(u3.x), w3, acc[0]);
    acc[1] = __hfma2(u2h2(u3.y), w3, acc[1]);
    acc[2] = __hfma2(u2h2(u3.z), w3, acc[2]);
    acc[3] = __hfma2(u2h2(u3.w), w3, acc[3]);
  }
  ushort8 o;
#pragma unroll
  for (int d = 0; d < 4; ++d) {
    o[2 * d]     = f2bf(__half2float(__low2half(acc[d])));
    o[2 * d + 1] = f2bf(__half2float(__high2half(acc[d])));
  }
  *reinterpret_cast<ushort8*>(&src2bf[n * DD + hg * DHD + li * 8]) = o;
}

// ---------------------------------------------------------------------------
// K4: xbf = bf16(LN1(src + src2bf @ W_out + b_out)). (R8-proven, 32-row)
// ---------------------------------------------------------------------------
__global__ __launch_bounds__(256) void k_outproj_mfma(const unsigned short* __restrict__ src2bf,
                                                      const unsigned short* __restrict__ Wof,
                                                      const float* __restrict__ bo,
                                                      const float* __restrict__ src,
                                                      const float* __restrict__ g1,
                                                      const float* __restrict__ b1g,
                                                      unsigned short* __restrict__ xbf) {
  __shared__ float rsum[32][4];
  __shared__ float rssq[32][4];
  const int t = threadIdx.x;
  const int w = t >> 6, lane = t & 63;
  const int lr = lane & 15, lgrp = lane >> 4;
  const long row0 = (long)blockIdx.x * 32;

  short8 af[2][8];
#pragma unroll
  for (int mt = 0; mt < 2; ++mt)
#pragma unroll
    for (int kt = 0; kt < 8; ++kt)
      af[mt][kt] = *reinterpret_cast<const short8*>(
          &src2bf[(row0 + mt * 16 + lr) * DD + kt * 32 + lgrp * 8]);

  f32x4 acc[2][4];
#pragma unroll
  for (int mt = 0; mt < 2; ++mt)
#pragma unroll
    for (int n = 0; n < 4; ++n) acc[mt][n] = (f32x4){0.f, 0.f, 0.f, 0.f};
#pragma unroll
  for (int n = 0; n < 4; ++n) {
    const int nt = w * 4 + n;
#pragma unroll
    for (int kt = 0; kt < 8; ++kt) {
      const short8 bf_ = *reinterpret_cast<const short8*>(&Wof[((nt * 8 + kt) * 64 + lane) * 8]);
#pragma unroll
      for (int mt = 0; mt < 2; ++mt)
        acc[mt][n] = __builtin_amdgcn_mfma_f32_16x16x32_bf16(af[mt][kt], bf_, acc[mt][n], 0, 0, 0);
    }
  }
  float bc[4], gc[4], bgc[4];
#pragma unroll
  for (int n = 0; n < 4; ++n) {
    const int col = w * 64 + n * 16 + lr;
    bc[n] = bo[col]; gc[n] = g1[col]; bgc[n] = b1g[col];
  }
  float vals[2][4][4];
#pragma unroll
  for (int mt = 0; mt < 2; ++mt)
#pragma unroll
    for (int j = 0; j < 4; ++j) {
      const int row = mt * 16 + lgrp * 4 + j;
      float s = 0.f, ss = 0.f;
#pragma unroll
      for (int n = 0; n < 4; ++n) {
        const int col = w * 64 + n * 16 + lr;
        const float v = acc[mt][n][j] + bc[n] + src[(row0 + row) * DD + col];
        vals[mt][n][j] = v;
        s += v; ss += v * v;
      }
#pragma unroll
      for (int m = 1; m <= 8; m <<= 1) { s += __shfl_xor(s, m, 64); ss += __shfl_xor(ss, m, 64); }
      if (lr == 0) { rsum[row][w] = s; rssq[row][w] = ss; }
    }
  __syncthreads();
#pragma unroll
  for (int mt = 0; mt < 2; ++mt)
#pragma unroll
    for (int j = 0; j < 4; ++j) {
      const int row = mt * 16 + lgrp * 4 + j;
      const float s  = rsum[row][0] + rsum[row][1] + rsum[row][2] + rsum[row][3];
      const float ss = rssq[row][0] + rssq[row][1] + rssq[row][2] + rssq[row][3];
      const float mean = s * (1.f / 256.f);
      const float inv  = rsqrtf(ss * (1.f / 256.f) - mean * mean + 1e-5f);
#pragma unroll
      for (int n = 0; n < 4; ++n) {
        const int col = w * 64 + n * 16 + lr;
        xbf[(row0 + row) * DD + col] = f2bf((vals[mt][n][j] - mean) * inv * gc[n] + bgc[n]);
      }
    }
}

// ---------------------------------------------------------------------------
// K5a: H in TILED layout; grid (340, 4) (R13-proven, plain stores).
// ---------------------------------------------------------------------------
__global__ __launch_bounds__(256) void k_ffn1e(const unsigned short* __restrict__ xbf,
                                               const unsigned short* __restrict__ W1f,
                                               const float* __restrict__ b1v,
                                               unsigned short* __restrict__ hfrag) {
  const int t = threadIdx.x;
  const int w = t >> 6, lane = t & 63;
  const int lr = lane & 15, lgrp = lane >> 4;
  const long row0 = (long)blockIdx.x * 64;
  const int hg = blockIdx.y;                // 256-hdim quarter (0..3)

  f32x4 acc[4][4];                          // [mm=hd tile][n=token tile]
#pragma unroll
  for (int mm = 0; mm < 4; ++mm)
#pragma unroll
    for (int n = 0; n < 4; ++n) acc[mm][n] = (f32x4){0.f, 0.f, 0.f, 0.f};

#pragma unroll
  for (int kt = 0; kt < 8; ++kt) {
    short8 bx[4];
#pragma unroll
    for (int n = 0; n < 4; ++n)
      bx[n] = *reinterpret_cast<const short8*>(
          &xbf[(row0 + n * 16 + lr) * DD + kt * 32 + lgrp * 8]);
#pragma unroll
    for (int mm = 0; mm < 4; ++mm) {
      const int ntg = hg * 16 + w * 4 + mm;
      const short8 aw1 = *reinterpret_cast<const short8*>(&W1f[((ntg * 8 + kt) * 64 + lane) * 8]);
#pragma unroll
      for (int n = 0; n < 4; ++n)
        acc[mm][n] = __builtin_amdgcn_mfma_f32_16x16x32_bf16(aw1, bx[n], acc[mm][n], 0, 0, 0);
    }
  }

#pragma unroll
  for (int mm = 0; mm < 4; ++mm) {
    const int ht = hg * 16 + w * 4 + mm;                      // hd-tile 0..63
    const float4 bq = *reinterpret_cast<const float4*>(&b1v[ht * 16 + lgrp * 4]);
#pragma unroll
    for (int n = 0; n < 4; ++n) {
      const long tt = (long)blockIdx.x * 4 + n;               // token-tile
      const long tbase = (tt * 64 + ht) * 256;
      int2 pk;
      pk.x = (int)pack2bf(fmaxf(acc[mm][n][0] + bq.x, 0.f),
                          fmaxf(acc[mm][n][1] + bq.y, 0.f));
      pk.y = (int)pack2bf(fmaxf(acc[mm][n][2] + bq.z, 0.f),
                          fmaxf(acc[mm][n][3] + bq.w, 0.f));
      *reinterpret_cast<int2*>(&hfrag[tbase + lane * 4]) = pk;
    }
  }
}

// ---------------------------------------------------------------------------
// K5b: out = LN2(xbf + H @ W2 + b2). (R10-proven, tiled-H reads, plain loads;
// nt store ONLY on out — write-once, never re-read).
// ---------------------------------------------------------------------------
__global__ __launch_bounds__(256) void k_ffn2t(const unsigned short* __restrict__ hfrag,
                                               const unsigned short* __restrict__ W2f,
                                               const float* __restrict__ b2v_,
                                               const unsigned short* __restrict__ xbf,
                                               const float* __restrict__ g2,
                                               const float* __restrict__ b2g,
                                               float* __restrict__ outp) {
  __shared__ float rsum[32][4];
  __shared__ float rssq[32][4];
  const int t = threadIdx.x;
  const int w = t >> 6, lane = t & 63;
  const int lr = lane & 15, lgrp = lane >> 4;
  const long row0 = (long)blockIdx.x * 32;

  f32x4 acc[2][4];
#pragma unroll
  for (int mt = 0; mt < 2; ++mt)
#pragma unroll
    for (int n = 0; n < 4; ++n) acc[mt][n] = (f32x4){0.f, 0.f, 0.f, 0.f};

#pragma unroll 4
  for (int kt = 0; kt < 32; ++kt) {
    short8 ha[2];
#pragma unroll
    for (int mt = 0; mt < 2; ++mt) {
      const long tt = (row0 >> 4) + mt;
      const long tb = (tt * 64 + kt * 2 + (lgrp >> 1)) * 256;
      const unsigned short* tp = &hfrag[tb + (lgrp & 1) * 128 + lr * 4];
      union { short8 s8; struct { int2 lo, hi; } p; } u;
      u.p.lo = *reinterpret_cast<const int2*>(tp);        // i 0..3
      u.p.hi = *reinterpret_cast<const int2*>(tp + 64);   // i 4..7
      ha[mt] = u.s8;
    }
#pragma unroll
    for (int n = 0; n < 4; ++n) {
      const int nt = w * 4 + n;
      const short8 bf_ = *reinterpret_cast<const short8*>(&W2f[((nt * 32 + kt) * 64 + lane) * 8]);
#pragma unroll
      for (int mt = 0; mt < 2; ++mt)
        acc[mt][n] = __builtin_amdgcn_mfma_f32_16x16x32_bf16(ha[mt], bf_, acc[mt][n], 0, 0, 0);
    }
  }

  float b2c[4], g2c[4], bgc[4];
#pragma unroll
  for (int n = 0; n < 4; ++n) {
    const int col = w * 64 + n * 16 + lr;
    b2c[n] = b2v_[col]; g2c[n] = g2[col]; bgc[n] = b2g[col];
  }
  float vals[2][4][4];
#pragma unroll
  for (int mt = 0; mt < 2; ++mt)
#pragma unroll
    for (int j = 0; j < 4; ++j) {
      const int row = mt * 16 + lgrp * 4 + j;
      float s = 0.f, ss = 0.f;
#pragma unroll
      for (int n = 0; n < 4; ++n) {
        const int col = w * 64 + n * 16 + lr;
        const float v = acc[mt][n][j] + b2c[n] + bf2f(xbf[(row0 + row) * DD + col]);
        vals[mt][n][j] = v;
        s += v; ss += v * v;
      }
#pragma unroll
      for (int m = 1; m <= 8; m <<= 1) { s += __shfl_xor(s, m, 64); ss += __shfl_xor(ss, m, 64); }
      if (lr == 0) { rsum[row][w] = s; rssq[row][w] = ss; }
    }
  __syncthreads();
#pragma unroll
  for (int mt = 0; mt < 2; ++mt)
#pragma unroll
    for (int j = 0; j < 4; ++j) {
      const int row = mt * 16 + lgrp * 4 + j;
      const float s  = rsum[row][0] + rsum[row][1] + rsum[row][2] + rsum[row][3];
      const float ss = rssq[row][0] + rssq[row][1] + rssq[row][2] + rssq[row][3];
      const float mean = s * (1.f / 256.f);
      const float inv  = rsqrtf(ss * (1.f / 256.f) - mean * mean + 1e-5f);
#pragma unroll
      for (int n = 0; n < 4; ++n) {
        const int col = w * 64 + n * 16 + lr;
        __builtin_nontemporal_store((vals[mt][n][j] - mean) * inv * g2c[n] + bgc[n],
                                    &outp[(row0 + row) * DD + col]);
      }
    }
}

extern "C" void kernel_launch(void* const* d_in, const int* in_sizes, int n_in,
                              void* d_out, int out_size, void* d_ws, size_t ws_size,
                              hipStream_t stream) {
  const float* src  = (const float*)d_in[0];
  const float* refp = (const float*)d_in[1];
  const float* pos  = (const float*)d_in[5];
  const float* Wv   = (const float*)d_in[6];
  const float* bv   = (const float*)d_in[7];
  const float* Woff = (const float*)d_in[8];
  const float* boff = (const float*)d_in[9];
  const float* Wat  = (const float*)d_in[10];
  const float* bat  = (const float*)d_in[11];
  const float* Wo   = (const float*)d_in[12];
  const float* bo   = (const float*)d_in[13];
  const float* g1   = (const float*)d_in[14];
  const float* b1g  = (const float*)d_in[15];
  const float* W1   = (const float*)d_in[16];
  const float* b1f  = (const float*)d_in[17];
  const float* W2   = (const float*)d_in[18];
  const float* b2f  = (const float*)d_in[19];
  const float* g2   = (const float*)d_in[20];
  const float* b2g  = (const float*)d_in[21];
  float* out = (float*)d_out;

  // workspace layout (R13-proven):
  unsigned short* valh   = (unsigned short*)d_ws;       // NTOK*256 u16 (fp16)
  unsigned short* offbf  = valh + NTOK * 256;           // NTOK*256 u16
  float*          attn   = (float*)(offbf + NTOK * 256);// NTOK*128 f32
  unsigned short* src2bf = (unsigned short*)(attn + NTOK * 128); // NTOK*256 u16
  unsigned short* xbf    = src2bf + NTOK * 256;         // NTOK*256 u16
  unsigned short* W1f = xbf + NTOK * 256;               // 262144
  unsigned short* W2f = W1f + 262144;                   // 262144
  unsigned short* Wvf = W2f + 262144;                   // 65536
  unsigned short* Wqf = Wvf + 65536;                    // 98304
  unsigned short* Wof = Wqf + 98304;                    // 65536
  unsigned short* frag_end = Wof + 65536;
  const size_t used  = (size_t)((char*)frag_end - (char*)d_ws);
  const size_t hneed = (size_t)NTOK * 1024 * 2;
  unsigned short* hfrag = (used + hneed <= ws_size) ? frag_end
                                                    : (unsigned short*)d_ws;

  hipLaunchKernelGGL(k_prep_all, dim3(2944), dim3(256), 0, stream,
                     W1, W2, Wv, Woff, Wat, Wo, W1f, W2f, Wvf, Wqf, Wof);
  hipLaunchKernelGGL(k_vq2, dim3((int)(NTOK / 32)), dim3(256), 0, stream,
                     src, pos, Wvf, bv, Wqf, boff, bat, valh, offbf, attn);
  hipLaunchKernelGGL(k_sample6, dim3((int)(NTOK / 8)), dim3(256), 0, stream,
                     valh, offbf, attn, refp, src2bf);
  hipLaunchKernelGGL(k_outproj_mfma, dim3((int)(NTOK / 32)), dim3(256), 0, stream,
                     src2bf, Wof, bo, src, g1, b1g, xbf);
  hipLaunchKernelGGL(k_ffn1e, dim3((int)(NTOK / 64), 4), dim3(256), 0, stream,
                     xbf, W1f, b1f, hfrag);
  hipLaunchKernelGGL(k_ffn2t, dim3((int)(NTOK / 32)), dim3(256), 0, stream,
                     hfrag, W2f, b2f, xbf, g2, b2g, out);
}

// Round 17
// 156.780 us; speedup vs baseline: 1.2464x; 1.0156x over previous
//
#include <hip/hip_runtime.h>
#include <hip/hip_fp16.h>

// Problem constants (fixed by setup_inputs)
constexpr int NB   = 4;
constexpr int SLEN = 5440;           // 64*64 + 32*32 + 16*16 + 8*8
constexpr long NTOK = (long)NB * SLEN; // 21760
constexpr int DD   = 256;
constexpr int NH   = 8;
constexpr int DHD  = 32;
constexpr int NL   = 4;
constexpr int NP   = 4;
constexpr int DFF  = 1024;

typedef __attribute__((ext_vector_type(8))) short short8;   // 8 x bf16
typedef __attribute__((ext_vector_type(8))) unsigned short ushort8;
typedef __attribute__((ext_vector_type(4))) float f32x4;

static __device__ __forceinline__ unsigned short f2bf(float x) {
  union { float f; unsigned int u; } v; v.f = x;
  unsigned int r = v.u + 0x7fffu + ((v.u >> 16) & 1u);   // RNE
  return (unsigned short)(r >> 16);
}
static __device__ __forceinline__ float bf2f(unsigned short u) {
  union { unsigned int i; float f; } v; v.i = ((unsigned int)u) << 16; return v.f;
}
static __device__ __forceinline__ unsigned int pack2bf(float lo, float hi) {
  return (unsigned int)f2bf(lo) | ((unsigned int)f2bf(hi) << 16);
}
static __device__ __forceinline__ unsigned int pack2h_dup(float a) {
  const unsigned int h = (unsigned int)__half_as_ushort(__float2half(a));
  return h | (h << 16);
}
static __device__ __forceinline__ __half2 u2h2(unsigned int u) {
  union { unsigned int i; __half2 h; } c; c.i = u; return c.h;
}

// B-fragment position for mfma_f32_16x16x32_bf16, weight K x N row-major.
// Dual-use: read as A-fragment it represents W^T (swapped-operand MFMA).
static __device__ __forceinline__ long fragpos(int k, int n, int KT) {
  const int kt = k >> 5, i = k & 7;
  const int lane = ((k >> 3) & 3) * 16 + (n & 15);
  const int nt = n >> 4;
  return (((long)(nt * KT + kt) * 64 + lane) * 8 + i);
}

// ---------------------------------------------------------------------------
// K_prep_all: fragment W1, W2, Wv, [Woff|Wattn], Wo into bf16 MFMA layout.
// ---------------------------------------------------------------------------
__global__ __launch_bounds__(256) void k_prep_all(const float* __restrict__ W1,
                                                  const float* __restrict__ W2,
                                                  const float* __restrict__ Wv,
                                                  const float* __restrict__ Woff,
                                                  const float* __restrict__ Wattn,
                                                  const float* __restrict__ Wo,
                                                  unsigned short* __restrict__ W1f,
                                                  unsigned short* __restrict__ W2f,
                                                  unsigned short* __restrict__ Wvf,
                                                  unsigned short* __restrict__ Wqf,
                                                  unsigned short* __restrict__ Wof) {
  const int g = blockIdx.x * 256 + threadIdx.x;
  if (g < 262144) {                       // W1: 256 x 1024, KT=8
    const int k = g >> 10, n = g & 1023;
    W1f[fragpos(k, n, 8)] = f2bf(W1[g]);
  } else if (g < 524288) {                // W2: 1024 x 256, KT=32
    const int g2 = g - 262144;
    const int k = g2 >> 8, n = g2 & 255;
    W2f[fragpos(k, n, 32)] = f2bf(W2[g2]);
  } else if (g < 589824) {                // Wv: 256 x 256, KT=8
    const int g2 = g - 524288;
    const int k = g2 >> 8, n = g2 & 255;
    Wvf[fragpos(k, n, 8)] = f2bf(Wv[g2]);
  } else if (g < 688128) {                // Wq fused: 256 x 384
    const int g2 = g - 589824;
    const int k = g2 / 384, n = g2 % 384;
    const float w = (n < 256) ? Woff[k * 256 + n] : Wattn[k * 128 + (n - 256)];
    Wqf[fragpos(k, n, 8)] = f2bf(w);
  } else if (g < 753664) {                // Wo: 256 x 256
    const int g2 = g - 688128;
    const int k = g2 >> 8, n = g2 & 255;
    Wof[fragpos(k, n, 8)] = f2bf(Wo[g2]);
  }
}

// ---------------------------------------------------------------------------
// K1+K2 fused (R13-proven): single 16KB LDS buffer.
// ---------------------------------------------------------------------------
__global__ __launch_bounds__(256) void k_vq2(const float* __restrict__ src,
                                             const float* __restrict__ pos,
                                             const unsigned short* __restrict__ Wvf,
                                             const float* __restrict__ bv,
                                             const unsigned short* __restrict__ Wqf,
                                             const float* __restrict__ boff,
                                             const float* __restrict__ battn,
                                             unsigned short* __restrict__ valh,
                                             unsigned short* __restrict__ offbf,
                                             float* __restrict__ attn) {
  __shared__ unsigned short Xs[32 * 256];   // 16 KB
  const int t = threadIdx.x;
  const int w = t >> 6, lane = t & 63;
  const int lr = lane & 15, lgrp = lane >> 4;
  const long row0 = (long)blockIdx.x * 32;
  const int r = t >> 3;
  const int c0 = (t & 7) * 32;

  {
    const float* sp = &src[(row0 + r) * DD + c0];
#pragma unroll
    for (int j = 0; j < 4; ++j) {
      const float4 a = *reinterpret_cast<const float4*>(&sp[j * 8 + 0]);
      const float4 b = *reinterpret_cast<const float4*>(&sp[j * 8 + 4]);
      short8 pk;
      pk[0] = (short)f2bf(a.x); pk[1] = (short)f2bf(a.y);
      pk[2] = (short)f2bf(a.z); pk[3] = (short)f2bf(a.w);
      pk[4] = (short)f2bf(b.x); pk[5] = (short)f2bf(b.y);
      pk[6] = (short)f2bf(b.z); pk[7] = (short)f2bf(b.w);
      int byte = r * 512 + (c0 + j * 8) * 2;
      byte ^= (r & 7) << 4;
      *reinterpret_cast<short8*>(reinterpret_cast<char*>(Xs) + byte) = pk;
    }
  }
  __syncthreads();

  short8 af[2][8];
#pragma unroll
  for (int mt = 0; mt < 2; ++mt)
#pragma unroll
    for (int kt = 0; kt < 8; ++kt) {
      const int row = mt * 16 + lr;
      int byte = row * 512 + kt * 64 + lgrp * 16;
      byte ^= (row & 7) << 4;
      af[mt][kt] = *reinterpret_cast<const short8*>(reinterpret_cast<const char*>(Xs) + byte);
    }

  // ---- phase V ----
  {
    f32x4 acc[2][4];
#pragma unroll
    for (int mt = 0; mt < 2; ++mt)
#pragma unroll
      for (int n = 0; n < 4; ++n) acc[mt][n] = (f32x4){0.f, 0.f, 0.f, 0.f};
#pragma unroll
    for (int n = 0; n < 4; ++n) {
      const int nt = w * 4 + n;
#pragma unroll
      for (int kt = 0; kt < 8; ++kt) {
        const short8 bf_ = *reinterpret_cast<const short8*>(&Wvf[((nt * 8 + kt) * 64 + lane) * 8]);
#pragma unroll
        for (int mt = 0; mt < 2; ++mt)
          acc[mt][n] = __builtin_amdgcn_mfma_f32_16x16x32_bf16(af[mt][kt], bf_, acc[mt][n], 0, 0, 0);
      }
    }
#pragma unroll
    for (int n = 0; n < 4; ++n) {
      const int col = w * 64 + n * 16 + lr;
      const float bb = bv[col];
#pragma unroll
      for (int mt = 0; mt < 2; ++mt)
#pragma unroll
        for (int j = 0; j < 4; ++j) {
          const int row = mt * 16 + lgrp * 4 + j;
          valh[(row0 + row) * DD + col] =
              __half_as_ushort(__float2half(acc[mt][n][j] + bb));
        }
    }
  }
  __syncthreads();

  // in-place Xs += pos
  {
    const float* pp = &pos[(row0 + r) * DD + c0];
#pragma unroll
    for (int j = 0; j < 4; ++j) {
      const float4 c = *reinterpret_cast<const float4*>(&pp[j * 8 + 0]);
      const float4 d = *reinterpret_cast<const float4*>(&pp[j * 8 + 4]);
      int byte = r * 512 + (c0 + j * 8) * 2;
      byte ^= (r & 7) << 4;
      short8 pk = *reinterpret_cast<const short8*>(reinterpret_cast<const char*>(Xs) + byte);
      pk[0] = (short)f2bf(bf2f((unsigned short)pk[0]) + c.x);
      pk[1] = (short)f2bf(bf2f((unsigned short)pk[1]) + c.y);
      pk[2] = (short)f2bf(bf2f((unsigned short)pk[2]) + c.z);
      pk[3] = (short)f2bf(bf2f((unsigned short)pk[3]) + c.w);
      pk[4] = (short)f2bf(bf2f((unsigned short)pk[4]) + d.x);
      pk[5] = (short)f2bf(bf2f((unsigned short)pk[5]) + d.y);
      pk[6] = (short)f2bf(bf2f((unsigned short)pk[6]) + d.z);
      pk[7] = (short)f2bf(bf2f((unsigned short)pk[7]) + d.w);
      *reinterpret_cast<short8*>(reinterpret_cast<char*>(Xs) + byte) = pk;
    }
  }
  __syncthreads();

#pragma unroll
  for (int mt = 0; mt < 2; ++mt)
#pragma unroll
    for (int kt = 0; kt < 8; ++kt) {
      const int row = mt * 16 + lr;
      int byte = row * 512 + kt * 64 + lgrp * 16;
      byte ^= (row & 7) << 4;
      af[mt][kt] = *reinterpret_cast<const short8*>(reinterpret_cast<const char*>(Xs) + byte);
    }

  // ---- phase Q ----
  {
    f32x4 acc[2][6];
#pragma unroll
    for (int mt = 0; mt < 2; ++mt)
#pragma unroll
      for (int i = 0; i < 6; ++i) acc[mt][i] = (f32x4){0.f, 0.f, 0.f, 0.f};
#pragma unroll
    for (int i = 0; i < 6; ++i) {
      const int ntg = w * 6 + i;
#pragma unroll
      for (int kt = 0; kt < 8; ++kt) {
        const short8 bf_ = *reinterpret_cast<const short8*>(&Wqf[((ntg * 8 + kt) * 64 + lane) * 8]);
#pragma unroll
        for (int mt = 0; mt < 2; ++mt)
          acc[mt][i] = __builtin_amdgcn_mfma_f32_16x16x32_bf16(af[mt][kt], bf_, acc[mt][i], 0, 0, 0);
      }
    }
#pragma unroll
    for (int i = 0; i < 6; ++i) {
      const int ntg = w * 6 + i;
      if (ntg < 16) {
        const int col = ntg * 16 + lr;
        const float bb = boff[col];
#pragma unroll
        for (int mt = 0; mt < 2; ++mt)
#pragma unroll
          for (int j = 0; j < 4; ++j) {
            const int row = mt * 16 + lgrp * 4 + j;
            offbf[(row0 + row) * 256 + col] = f2bf(acc[mt][i][j] + bb);
          }
      } else {
        const int na = ntg - 16;       // head index
        const float bb = battn[na * 16 + lr];
#pragma unroll
        for (int mt = 0; mt < 2; ++mt)
#pragma unroll
          for (int j = 0; j < 4; ++j) {
            const int row = mt * 16 + lgrp * 4 + j;
            const float v = acc[mt][i][j] + bb;
            float m = v;
#pragma unroll
            for (int d_ = 1; d_ <= 8; d_ <<= 1) m = fmaxf(m, __shfl_xor(m, d_, 16));
            const float e = __expf(v - m);
            float s = e;
#pragma unroll
            for (int d_ = 1; d_ <= 8; d_ <<= 1) s += __shfl_xor(s, d_, 16);
            attn[(row0 + row) * 128 + na * 16 + lr] = e / s;
          }
      }
    }
  }
}

// ---------------------------------------------------------------------------
// K3: deformable sampling v7 (R12-proven). FP16 value -> pure v_pk_fma_f16.
// ---------------------------------------------------------------------------
__global__ __launch_bounds__(256) void k_sample6(const unsigned short* __restrict__ valh,
                                                 const unsigned short* __restrict__ offbf,
                                                 const float* __restrict__ attn,
                                                 const float* __restrict__ refp,
                                                 unsigned short* __restrict__ src2bf) {
  __shared__ int4  sIdx[4][2][8][16];   // 16 KB
  __shared__ uint4 sWgt[4][2][8][16];   // 16 KB (4 x dup-half2)
  const int t = threadIdx.x;
  const int w = t >> 6, lane = t & 63;
  const int tok = lane >> 5, hg = (lane >> 2) & 7, li = lane & 3;
  const int B = blockIdx.x;
  const int bimg = (B & 7) >> 1;
  const int ii = ((B >> 3) << 1) + (B & 1);       // 0..679
  const long n = (long)bimg * SLEN + ii * 8 + w * 2 + tok;
  const long bOff = (long)bimg * SLEN;

  const int   WlA[4] = {64, 32, 16, 8};
  const float rWA[4] = {1.f / 64.f, 1.f / 32.f, 1.f / 16.f, 1.f / 8.f};
  const int   stA[4] = {0, 4096, 5120, 5376};

#pragma unroll
  for (int q = 0; q < 4; ++q) {       // level = q, point-in-level = li
    const int pt = q * 4 + li;
    const int Wi = WlA[q];
    const float Wf = (float)Wi, rW = rWA[q];
    const float rx = refp[(n * 4 + q) * 2 + 0];
    const float ry = refp[(n * 4 + q) * 2 + 1];
    const float aw = attn[n * 128 + hg * 16 + pt];
    const int oi = ((hg * 4 + q) * 4 + li) * 2;
    const unsigned int opk = *reinterpret_cast<const unsigned int*>(&offbf[n * 256 + oi]);
    const float ox = bf2f((unsigned short)(opk & 0xffff));
    const float oy = bf2f((unsigned short)(opk >> 16));
    const float px = (rx + ox * rW) * Wf - 0.5f;
    const float py = (ry + oy * rW) * Wf - 0.5f;
    const float x0f = floorf(px), y0f = floorf(py);
    const float fx = px - x0f, fy = py - y0f;
    const int x0 = (int)x0f, y0 = (int)y0f;
    int   ic[4];
    float wc[4];
#pragma unroll
    for (int c = 0; c < 4; ++c) {
      const int dx = c & 1, dy = c >> 1;
      const int xi = x0 + dx, yi = y0 + dy;
      const float cw = (dx ? fx : 1.f - fx) * (dy ? fy : 1.f - fy);
      const bool valid = (xi >= 0) && (xi < Wi) && (yi >= 0) && (yi < Wi);
      const int xc = min(max(xi, 0), Wi - 1);
      const int yc = min(max(yi, 0), Wi - 1);
      const long flat = stA[q] + yc * Wi + xc;
      ic[c] = (int)((bOff + flat) * DD + hg * DHD);
      wc[c] = aw * cw * (valid ? 1.f : 0.f);
    }
    const int slot = pt ^ hg;
    sIdx[w][tok][hg][slot] = make_int4(ic[0], ic[1], ic[2], ic[3]);
    sWgt[w][tok][hg][slot] = make_uint4(pack2h_dup(wc[0]), pack2h_dup(wc[1]),
                                        pack2h_dup(wc[2]), pack2h_dup(wc[3]));
  }
  __syncthreads();

  __half2 acc[4];
#pragma unroll
  for (int d = 0; d < 4; ++d) acc[d] = __float2half2_rn(0.f);
#pragma unroll 4
  for (int pt = 0; pt < 16; ++pt) {
    const int slot = pt ^ hg;
    const int4  ia = sIdx[w][tok][hg][slot];
    const uint4 wp = sWgt[w][tok][hg][slot];
    const uint4 u0 = *reinterpret_cast<const uint4*>(&valh[(long)ia.x + li * 8]);
    const uint4 u1 = *reinterpret_cast<const uint4*>(&valh[(long)ia.y + li * 8]);
    const uint4 u2 = *reinterpret_cast<const uint4*>(&valh[(long)ia.z + li * 8]);
    const uint4 u3 = *reinterpret_cast<const uint4*>(&valh[(long)ia.w + li * 8]);
    const __half2 w0 = u2h2(wp.x), w1 = u2h2(wp.y), w2 = u2h2(wp.z), w3 = u2h2(wp.w);
    acc[0] = __hfma2(u2h2(u0.x), w0, acc[0]);
    acc[1] = __hfma2(u2h2(u0.y), w0, acc[1]);
    acc[2] = __hfma2(u2h2(u0.z), w0, acc[2]);
    acc[3] = __hfma2(u2h2(u0.w), w0, acc[3]);
    acc[0] = __hfma2(u2h2(u1.x), w1, acc[0]);
    acc[1] = __hfma2(u2h2(u1.y), w1, acc[1]);
    acc[2] = __hfma2(u2h2(u1.z), w1, acc[2]);
    acc[3] = __hfma2(u2h2(u1.w), w1, acc[3]);
    acc[0] = __hfma2(u2h2(u2.x), w2, acc[0]);
    acc[1] = __hfma2(u2h2(u2.y), w2, acc[1]);
    acc[2] = __hfma2(u2h2(u2.z), w2, acc[2]);
    acc[3] = __hfma2(u2h2(u2.w), w2, acc[3]);
    acc[0] = __hfma2(u2h2(u3.x), w3, acc[0]);
    acc[1] = __hfma2(u2h2(u3.y), w3, acc[1]);
    acc[2] = __hfma2(u2h2(u3.z), w3, acc[2]);
    acc[3] = __hfma2(u2h2(u3.w), w3, acc[3]);
  }
  ushort8 o;
#pragma unroll
  for (int d = 0; d < 4; ++d) {
    o[2 * d]     = f2bf(__half2float(__low2half(acc[d])));
    o[2 * d + 1] = f2bf(__half2float(__high2half(acc[d])));
  }
  *reinterpret_cast<ushort8*>(&src2bf[n * DD + hg * DHD + li * 8]) = o;
}

// ---------------------------------------------------------------------------
// K4: xbf = bf16(LN1(src + src2bf @ W_out + b_out)). (R8-proven, 32-row)
// ---------------------------------------------------------------------------
__global__ __launch_bounds__(256) void k_outproj_mfma(const unsigned short* __restrict__ src2bf,
                                                      const unsigned short* __restrict__ Wof,
                                                      const float* __restrict__ bo,
                                                      const float* __restrict__ src,
                                                      const float* __restrict__ g1,
                                                      const float* __restrict__ b1g,
                                                      unsigned short* __restrict__ xbf) {
  __shared__ float rsum[32][4];
  __shared__ float rssq[32][4];
  const int t = threadIdx.x;
  const int w = t >> 6, lane = t & 63;
  const int lr = lane & 15, lgrp = lane >> 4;
  const long row0 = (long)blockIdx.x * 32;

  short8 af[2][8];
#pragma unroll
  for (int mt = 0; mt < 2; ++mt)
#pragma unroll
    for (int kt = 0; kt < 8; ++kt)
      af[mt][kt] = *reinterpret_cast<const short8*>(
          &src2bf[(row0 + mt * 16 + lr) * DD + kt * 32 + lgrp * 8]);

  f32x4 acc[2][4];
#pragma unroll
  for (int mt = 0; mt < 2; ++mt)
#pragma unroll
    for (int n = 0; n < 4; ++n) acc[mt][n] = (f32x4){0.f, 0.f, 0.f, 0.f};
#pragma unroll
  for (int n = 0; n < 4; ++n) {
    const int nt = w * 4 + n;
#pragma unroll
    for (int kt = 0; kt < 8; ++kt) {
      const short8 bf_ = *reinterpret_cast<const short8*>(&Wof[((nt * 8 + kt) * 64 + lane) * 8]);
#pragma unroll
      for (int mt = 0; mt < 2; ++mt)
        acc[mt][n] = __builtin_amdgcn_mfma_f32_16x16x32_bf16(af[mt][kt], bf_, acc[mt][n], 0, 0, 0);
    }
  }
  float bc[4], gc[4], bgc[4];
#pragma unroll
  for (int n = 0; n < 4; ++n) {
    const int col = w * 64 + n * 16 + lr;
    bc[n] = bo[col]; gc[n] = g1[col]; bgc[n] = b1g[col];
  }
  float vals[2][4][4];
#pragma unroll
  for (int mt = 0; mt < 2; ++mt)
#pragma unroll
    for (int j = 0; j < 4; ++j) {
      const int row = mt * 16 + lgrp * 4 + j;
      float s = 0.f, ss = 0.f;
#pragma unroll
      for (int n = 0; n < 4; ++n) {
        const int col = w * 64 + n * 16 + lr;
        const float v = acc[mt][n][j] + bc[n] + src[(row0 + row) * DD + col];
        vals[mt][n][j] = v;
        s += v; ss += v * v;
      }
#pragma unroll
      for (int m = 1; m <= 8; m <<= 1) { s += __shfl_xor(s, m, 64); ss += __shfl_xor(ss, m, 64); }
      if (lr == 0) { rsum[row][w] = s; rssq[row][w] = ss; }
    }
  __syncthreads();
#pragma unroll
  for (int mt = 0; mt < 2; ++mt)
#pragma unroll
    for (int j = 0; j < 4; ++j) {
      const int row = mt * 16 + lgrp * 4 + j;
      const float s  = rsum[row][0] + rsum[row][1] + rsum[row][2] + rsum[row][3];
      const float ss = rssq[row][0] + rssq[row][1] + rssq[row][2] + rssq[row][3];
      const float mean = s * (1.f / 256.f);
      const float inv  = rsqrtf(ss * (1.f / 256.f) - mean * mean + 1e-5f);
#pragma unroll
      for (int n = 0; n < 4; ++n) {
        const int col = w * 64 + n * 16 + lr;
        xbf[(row0 + row) * DD + col] = f2bf((vals[mt][n][j] - mean) * inv * gc[n] + bgc[n]);
      }
    }
}

// ---------------------------------------------------------------------------
// K5a: H in TILED layout (R13-proven). NEW: flat grid (1360) with XCD
// co-location swizzle — the 4 hd-quarter blocks of one token-tile get IDs
// congruent mod 8, landing on the SAME XCD so xbf's 4x reuse hits one L2.
// ---------------------------------------------------------------------------
__global__ __launch_bounds__(256) void k_ffn1e(const unsigned short* __restrict__ xbf,
                                               const unsigned short* __restrict__ W1f,
                                               const float* __restrict__ b1v,
                                               unsigned short* __restrict__ hfrag) {
  const int t = threadIdx.x;
  const int w = t >> 6, lane = t & 63;
  const int lr = lane & 15, lgrp = lane >> 4;
  // bijective unswizzle: bid -> (x = token-tile 0..339, y = hd-quarter 0..3)
  const int bid = blockIdx.x;
  int x, hg;
  if (bid < 1344) { x = (bid & 7) + 8 * (bid >> 5); hg = (bid >> 3) & 3; }
  else            { const int rr = bid - 1344; x = 336 + (rr & 3); hg = rr >> 2; }
  const long row0 = (long)x * 64;

  f32x4 acc[4][4];                          // [mm=hd tile][n=token tile]
#pragma unroll
  for (int mm = 0; mm < 4; ++mm)
#pragma unroll
    for (int n = 0; n < 4; ++n) acc[mm][n] = (f32x4){0.f, 0.f, 0.f, 0.f};

#pragma unroll
  for (int kt = 0; kt < 8; ++kt) {
    short8 bx[4];
#pragma unroll
    for (int n = 0; n < 4; ++n)
      bx[n] = *reinterpret_cast<const short8*>(
          &xbf[(row0 + n * 16 + lr) * DD + kt * 32 + lgrp * 8]);
#pragma unroll
    for (int mm = 0; mm < 4; ++mm) {
      const int ntg = hg * 16 + w * 4 + mm;
      const short8 aw1 = *reinterpret_cast<const short8*>(&W1f[((ntg * 8 + kt) * 64 + lane) * 8]);
#pragma unroll
      for (int n = 0; n < 4; ++n)
        acc[mm][n] = __builtin_amdgcn_mfma_f32_16x16x32_bf16(aw1, bx[n], acc[mm][n], 0, 0, 0);
    }
  }

#pragma unroll
  for (int mm = 0; mm < 4; ++mm) {
    const int ht = hg * 16 + w * 4 + mm;                      // hd-tile 0..63
    const float4 bq = *reinterpret_cast<const float4*>(&b1v[ht * 16 + lgrp * 4]);
#pragma unroll
    for (int n = 0; n < 4; ++n) {
      const long tt = (long)x * 4 + n;                        // token-tile
      const long tbase = (tt * 64 + ht) * 256;
      int2 pk;
      pk.x = (int)pack2bf(fmaxf(acc[mm][n][0] + bq.x, 0.f),
                          fmaxf(acc[mm][n][1] + bq.y, 0.f));
      pk.y = (int)pack2bf(fmaxf(acc[mm][n][2] + bq.z, 0.f),
                          fmaxf(acc[mm][n][3] + bq.w, 0.f));
      *reinterpret_cast<int2*>(&hfrag[tbase + lane * 4]) = pk;
    }
  }
}

// ---------------------------------------------------------------------------
// K5b: out = LN2(xbf + H @ W2 + b2). (R16-proven: plain H loads, nt out store)
// ---------------------------------------------------------------------------
__global__ __launch_bounds__(256) void k_ffn2t(const unsigned short* __restrict__ hfrag,
                                               const unsigned short* __restrict__ W2f,
                                               const float* __restrict__ b2v_,
                                               const unsigned short* __restrict__ xbf,
                                               const float* __restrict__ g2,
                                               const float* __restrict__ b2g,
                                               float* __restrict__ outp) {
  __shared__ float rsum[32][4];
  __shared__ float rssq[32][4];
  const int t = threadIdx.x;
  const int w = t >> 6, lane = t & 63;
  const int lr = lane & 15, lgrp = lane >> 4;
  const long row0 = (long)blockIdx.x * 32;

  f32x4 acc[2][4];
#pragma unroll
  for (int mt = 0; mt < 2; ++mt)
#pragma unroll
    for (int n = 0; n < 4; ++n) acc[mt][n] = (f32x4){0.f, 0.f, 0.f, 0.f};

#pragma unroll 4
  for (int kt = 0; kt < 32; ++kt) {
    short8 ha[2];
#pragma unroll
    for (int mt = 0; mt < 2; ++mt) {
      const long tt = (row0 >> 4) + mt;
      const long tb = (tt * 64 + kt * 2 + (lgrp >> 1)) * 256;
      const unsigned short* tp = &hfrag[tb + (lgrp & 1) * 128 + lr * 4];
      union { short8 s8; struct { int2 lo, hi; } p; } u;
      u.p.lo = *reinterpret_cast<const int2*>(tp);        // i 0..3
      u.p.hi = *reinterpret_cast<const int2*>(tp + 64);   // i 4..7
      ha[mt] = u.s8;
    }
#pragma unroll
    for (int n = 0; n < 4; ++n) {
      const int nt = w * 4 + n;
      const short8 bf_ = *reinterpret_cast<const short8*>(&W2f[((nt * 32 + kt) * 64 + lane) * 8]);
#pragma unroll
      for (int mt = 0; mt < 2; ++mt)
        acc[mt][n] = __builtin_amdgcn_mfma_f32_16x16x32_bf16(ha[mt], bf_, acc[mt][n], 0, 0, 0);
    }
  }

  float b2c[4], g2c[4], bgc[4];
#pragma unroll
  for (int n = 0; n < 4; ++n) {
    const int col = w * 64 + n * 16 + lr;
    b2c[n] = b2v_[col]; g2c[n] = g2[col]; bgc[n] = b2g[col];
  }
  float vals[2][4][4];
#pragma unroll
  for (int mt = 0; mt < 2; ++mt)
#pragma unroll
    for (int j = 0; j < 4; ++j) {
      const int row = mt * 16 + lgrp * 4 + j;
      float s = 0.f, ss = 0.f;
#pragma unroll
      for (int n = 0; n < 4; ++n) {
        const int col = w * 64 + n * 16 + lr;
        const float v = acc[mt][n][j] + b2c[n] + bf2f(xbf[(row0 + row) * DD + col]);
        vals[mt][n][j] = v;
        s += v; ss += v * v;
      }
#pragma unroll
      for (int m = 1; m <= 8; m <<= 1) { s += __shfl_xor(s, m, 64); ss += __shfl_xor(ss, m, 64); }
      if (lr == 0) { rsum[row][w] = s; rssq[row][w] = ss; }
    }
  __syncthreads();
#pragma unroll
  for (int mt = 0; mt < 2; ++mt)
#pragma unroll
    for (int j = 0; j < 4; ++j) {
      const int row = mt * 16 + lgrp * 4 + j;
      const float s  = rsum[row][0] + rsum[row][1] + rsum[row][2] + rsum[row][3];
      const float ss = rssq[row][0] + rssq[row][1] + rssq[row][2] + rssq[row][3];
      const float mean = s * (1.f / 256.f);
      const float inv  = rsqrtf(ss * (1.f / 256.f) - mean * mean + 1e-5f);
#pragma unroll
      for (int n = 0; n < 4; ++n) {
        const int col = w * 64 + n * 16 + lr;
        __builtin_nontemporal_store((vals[mt][n][j] - mean) * inv * g2c[n] + bgc[n],
                                    &outp[(row0 + row) * DD + col]);
      }
    }
}

extern "C" void kernel_launch(void* const* d_in, const int* in_sizes, int n_in,
                              void* d_out, int out_size, void* d_ws, size_t ws_size,
                              hipStream_t stream) {
  const float* src  = (const float*)d_in[0];
  const float* refp = (const float*)d_in[1];
  const float* pos  = (const float*)d_in[5];
  const float* Wv   = (const float*)d_in[6];
  const float* bv   = (const float*)d_in[7];
  const float* Woff = (const float*)d_in[8];
  const float* boff = (const float*)d_in[9];
  const float* Wat  = (const float*)d_in[10];
  const float* bat  = (const float*)d_in[11];
  const float* Wo   = (const float*)d_in[12];
  const float* bo   = (const float*)d_in[13];
  const float* g1   = (const float*)d_in[14];
  const float* b1g  = (const float*)d_in[15];
  const float* W1   = (const float*)d_in[16];
  const float* b1f  = (const float*)d_in[17];
  const float* W2   = (const float*)d_in[18];
  const float* b2f  = (const float*)d_in[19];
  const float* g2   = (const float*)d_in[20];
  const float* b2g  = (const float*)d_in[21];
  float* out = (float*)d_out;

  // workspace layout (R13-proven):
  unsigned short* valh   = (unsigned short*)d_ws;       // NTOK*256 u16 (fp16)
  unsigned short* offbf  = valh + NTOK * 256;           // NTOK*256 u16
  float*          attn   = (float*)(offbf + NTOK * 256);// NTOK*128 f32
  unsigned short* src2bf = (unsigned short*)(attn + NTOK * 128); // NTOK*256 u16
  unsigned short* xbf    = src2bf + NTOK * 256;         // NTOK*256 u16
  unsigned short* W1f = xbf + NTOK * 256;               // 262144
  unsigned short* W2f = W1f + 262144;                   // 262144
  unsigned short* Wvf = W2f + 262144;                   // 65536
  unsigned short* Wqf = Wvf + 65536;                    // 98304
  unsigned short* Wof = Wqf + 98304;                    // 65536
  unsigned short* frag_end = Wof + 65536;
  const size_t used  = (size_t)((char*)frag_end - (char*)d_ws);
  const size_t hneed = (size_t)NTOK * 1024 * 2;
  unsigned short* hfrag = (used + hneed <= ws_size) ? frag_end
                                                    : (unsigned short*)d_ws;

  hipLaunchKernelGGL(k_prep_all, dim3(2944), dim3(256), 0, stream,
                     W1, W2, Wv, Woff, Wat, Wo, W1f, W2f, Wvf, Wqf, Wof);
  hipLaunchKernelGGL(k_vq2, dim3((int)(NTOK / 32)), dim3(256), 0, stream,
                     src, pos, Wvf, bv, Wqf, boff, bat, valh, offbf, attn);
  hipLaunchKernelGGL(k_sample6, dim3((int)(NTOK / 8)), dim3(256), 0, stream,
                     valh, offbf, attn, refp, src2bf);
  hipLaunchKernelGGL(k_outproj_mfma, dim3((int)(NTOK / 32)), dim3(256), 0, stream,
                     src2bf, Wof, bo, src, g1, b1g, xbf);
  hipLaunchKernelGGL(k_ffn1e, dim3(1360), dim3(256), 0, stream,
                     xbf, W1f, b1f, hfrag);
  hipLaunchKernelGGL(k_ffn2t, dim3((int)(NTOK / 32)), dim3(256), 0, stream,
                     hfrag, W2f, b2f, xbf, g2, b2g, out);
}

// Round 18
// 155.064 us; speedup vs baseline: 1.2602x; 1.0111x over previous
//
#include <hip/hip_runtime.h>
#include <hip/hip_fp16.h>

// Problem constants (fixed by setup_inputs)
constexpr int NB   = 4;
constexpr int SLEN = 5440;           // 64*64 + 32*32 + 16*16 + 8*8
constexpr long NTOK = (long)NB * SLEN; // 21760
constexpr int DD   = 256;
constexpr int NH   = 8;
constexpr int DHD  = 32;
constexpr int NL   = 4;
constexpr int NP   = 4;
constexpr int DFF  = 1024;

typedef __attribute__((ext_vector_type(8))) short short8;   // 8 x bf16
typedef __attribute__((ext_vector_type(8))) unsigned short ushort8;
typedef __attribute__((ext_vector_type(4))) float f32x4;

static __device__ __forceinline__ unsigned short f2bf(float x) {
  union { float f; unsigned int u; } v; v.f = x;
  unsigned int r = v.u + 0x7fffu + ((v.u >> 16) & 1u);   // RNE
  return (unsigned short)(r >> 16);
}
static __device__ __forceinline__ float bf2f(unsigned short u) {
  union { unsigned int i; float f; } v; v.i = ((unsigned int)u) << 16; return v.f;
}
static __device__ __forceinline__ unsigned int pack2bf(float lo, float hi) {
  return (unsigned int)f2bf(lo) | ((unsigned int)f2bf(hi) << 16);
}
static __device__ __forceinline__ unsigned int pack2h_dup(float a) {
  const unsigned int h = (unsigned int)__half_as_ushort(__float2half(a));
  return h | (h << 16);
}
static __device__ __forceinline__ __half2 u2h2(unsigned int u) {
  union { unsigned int i; __half2 h; } c; c.i = u; return c.h;
}

// B-fragment position for mfma_f32_16x16x32_bf16, weight K x N row-major.
// Dual-use: read as A-fragment it represents W^T (swapped-operand MFMA).
static __device__ __forceinline__ long fragpos(int k, int n, int KT) {
  const int kt = k >> 5, i = k & 7;
  const int lane = ((k >> 3) & 3) * 16 + (n & 15);
  const int nt = n >> 4;
  return (((long)(nt * KT + kt) * 64 + lane) * 8 + i);
}

// ---------------------------------------------------------------------------
// K_prep_all: fragment W1, W2, Wv, [Woff|Wattn], Wo into bf16 MFMA layout.
// ---------------------------------------------------------------------------
__global__ __launch_bounds__(256) void k_prep_all(const float* __restrict__ W1,
                                                  const float* __restrict__ W2,
                                                  const float* __restrict__ Wv,
                                                  const float* __restrict__ Woff,
                                                  const float* __restrict__ Wattn,
                                                  const float* __restrict__ Wo,
                                                  unsigned short* __restrict__ W1f,
                                                  unsigned short* __restrict__ W2f,
                                                  unsigned short* __restrict__ Wvf,
                                                  unsigned short* __restrict__ Wqf,
                                                  unsigned short* __restrict__ Wof) {
  const int g = blockIdx.x * 256 + threadIdx.x;
  if (g < 262144) {                       // W1: 256 x 1024, KT=8
    const int k = g >> 10, n = g & 1023;
    W1f[fragpos(k, n, 8)] = f2bf(W1[g]);
  } else if (g < 524288) {                // W2: 1024 x 256, KT=32
    const int g2 = g - 262144;
    const int k = g2 >> 8, n = g2 & 255;
    W2f[fragpos(k, n, 32)] = f2bf(W2[g2]);
  } else if (g < 589824) {                // Wv: 256 x 256, KT=8
    const int g2 = g - 524288;
    const int k = g2 >> 8, n = g2 & 255;
    Wvf[fragpos(k, n, 8)] = f2bf(Wv[g2]);
  } else if (g < 688128) {                // Wq fused: 256 x 384
    const int g2 = g - 589824;
    const int k = g2 / 384, n = g2 % 384;
    const float w = (n < 256) ? Woff[k * 256 + n] : Wattn[k * 128 + (n - 256)];
    Wqf[fragpos(k, n, 8)] = f2bf(w);
  } else if (g < 753664) {                // Wo: 256 x 256
    const int g2 = g - 688128;
    const int k = g2 >> 8, n = g2 & 255;
    Wof[fragpos(k, n, 8)] = f2bf(Wo[g2]);
  }
}

// ---------------------------------------------------------------------------
// K1+K2 fused (R13-proven): single 16KB LDS buffer.
// ---------------------------------------------------------------------------
__global__ __launch_bounds__(256) void k_vq2(const float* __restrict__ src,
                                             const float* __restrict__ pos,
                                             const unsigned short* __restrict__ Wvf,
                                             const float* __restrict__ bv,
                                             const unsigned short* __restrict__ Wqf,
                                             const float* __restrict__ boff,
                                             const float* __restrict__ battn,
                                             unsigned short* __restrict__ valh,
                                             unsigned short* __restrict__ offbf,
                                             float* __restrict__ attn) {
  __shared__ unsigned short Xs[32 * 256];   // 16 KB
  const int t = threadIdx.x;
  const int w = t >> 6, lane = t & 63;
  const int lr = lane & 15, lgrp = lane >> 4;
  const long row0 = (long)blockIdx.x * 32;
  const int r = t >> 3;
  const int c0 = (t & 7) * 32;

  {
    const float* sp = &src[(row0 + r) * DD + c0];
#pragma unroll
    for (int j = 0; j < 4; ++j) {
      const float4 a = *reinterpret_cast<const float4*>(&sp[j * 8 + 0]);
      const float4 b = *reinterpret_cast<const float4*>(&sp[j * 8 + 4]);
      short8 pk;
      pk[0] = (short)f2bf(a.x); pk[1] = (short)f2bf(a.y);
      pk[2] = (short)f2bf(a.z); pk[3] = (short)f2bf(a.w);
      pk[4] = (short)f2bf(b.x); pk[5] = (short)f2bf(b.y);
      pk[6] = (short)f2bf(b.z); pk[7] = (short)f2bf(b.w);
      int byte = r * 512 + (c0 + j * 8) * 2;
      byte ^= (r & 7) << 4;
      *reinterpret_cast<short8*>(reinterpret_cast<char*>(Xs) + byte) = pk;
    }
  }
  __syncthreads();

  short8 af[2][8];
#pragma unroll
  for (int mt = 0; mt < 2; ++mt)
#pragma unroll
    for (int kt = 0; kt < 8; ++kt) {
      const int row = mt * 16 + lr;
      int byte = row * 512 + kt * 64 + lgrp * 16;
      byte ^= (row & 7) << 4;
      af[mt][kt] = *reinterpret_cast<const short8*>(reinterpret_cast<const char*>(Xs) + byte);
    }

  // ---- phase V ----
  {
    f32x4 acc[2][4];
#pragma unroll
    for (int mt = 0; mt < 2; ++mt)
#pragma unroll
      for (int n = 0; n < 4; ++n) acc[mt][n] = (f32x4){0.f, 0.f, 0.f, 0.f};
#pragma unroll
    for (int n = 0; n < 4; ++n) {
      const int nt = w * 4 + n;
#pragma unroll
      for (int kt = 0; kt < 8; ++kt) {
        const short8 bf_ = *reinterpret_cast<const short8*>(&Wvf[((nt * 8 + kt) * 64 + lane) * 8]);
#pragma unroll
        for (int mt = 0; mt < 2; ++mt)
          acc[mt][n] = __builtin_amdgcn_mfma_f32_16x16x32_bf16(af[mt][kt], bf_, acc[mt][n], 0, 0, 0);
      }
    }
#pragma unroll
    for (int n = 0; n < 4; ++n) {
      const int col = w * 64 + n * 16 + lr;
      const float bb = bv[col];
#pragma unroll
      for (int mt = 0; mt < 2; ++mt)
#pragma unroll
        for (int j = 0; j < 4; ++j) {
          const int row = mt * 16 + lgrp * 4 + j;
          valh[(row0 + row) * DD + col] =
              __half_as_ushort(__float2half(acc[mt][n][j] + bb));
        }
    }
  }
  __syncthreads();

  // in-place Xs += pos
  {
    const float* pp = &pos[(row0 + r) * DD + c0];
#pragma unroll
    for (int j = 0; j < 4; ++j) {
      const float4 c = *reinterpret_cast<const float4*>(&pp[j * 8 + 0]);
      const float4 d = *reinterpret_cast<const float4*>(&pp[j * 8 + 4]);
      int byte = r * 512 + (c0 + j * 8) * 2;
      byte ^= (r & 7) << 4;
      short8 pk = *reinterpret_cast<const short8*>(reinterpret_cast<const char*>(Xs) + byte);
      pk[0] = (short)f2bf(bf2f((unsigned short)pk[0]) + c.x);
      pk[1] = (short)f2bf(bf2f((unsigned short)pk[1]) + c.y);
      pk[2] = (short)f2bf(bf2f((unsigned short)pk[2]) + c.z);
      pk[3] = (short)f2bf(bf2f((unsigned short)pk[3]) + c.w);
      pk[4] = (short)f2bf(bf2f((unsigned short)pk[4]) + d.x);
      pk[5] = (short)f2bf(bf2f((unsigned short)pk[5]) + d.y);
      pk[6] = (short)f2bf(bf2f((unsigned short)pk[6]) + d.z);
      pk[7] = (short)f2bf(bf2f((unsigned short)pk[7]) + d.w);
      *reinterpret_cast<short8*>(reinterpret_cast<char*>(Xs) + byte) = pk;
    }
  }
  __syncthreads();

#pragma unroll
  for (int mt = 0; mt < 2; ++mt)
#pragma unroll
    for (int kt = 0; kt < 8; ++kt) {
      const int row = mt * 16 + lr;
      int byte = row * 512 + kt * 64 + lgrp * 16;
      byte ^= (row & 7) << 4;
      af[mt][kt] = *reinterpret_cast<const short8*>(reinterpret_cast<const char*>(Xs) + byte);
    }

  // ---- phase Q ----
  {
    f32x4 acc[2][6];
#pragma unroll
    for (int mt = 0; mt < 2; ++mt)
#pragma unroll
      for (int i = 0; i < 6; ++i) acc[mt][i] = (f32x4){0.f, 0.f, 0.f, 0.f};
#pragma unroll
    for (int i = 0; i < 6; ++i) {
      const int ntg = w * 6 + i;
#pragma unroll
      for (int kt = 0; kt < 8; ++kt) {
        const short8 bf_ = *reinterpret_cast<const short8*>(&Wqf[((ntg * 8 + kt) * 64 + lane) * 8]);
#pragma unroll
        for (int mt = 0; mt < 2; ++mt)
          acc[mt][i] = __builtin_amdgcn_mfma_f32_16x16x32_bf16(af[mt][kt], bf_, acc[mt][i], 0, 0, 0);
      }
    }
#pragma unroll
    for (int i = 0; i < 6; ++i) {
      const int ntg = w * 6 + i;
      if (ntg < 16) {
        const int col = ntg * 16 + lr;
        const float bb = boff[col];
#pragma unroll
        for (int mt = 0; mt < 2; ++mt)
#pragma unroll
          for (int j = 0; j < 4; ++j) {
            const int row = mt * 16 + lgrp * 4 + j;
            offbf[(row0 + row) * 256 + col] = f2bf(acc[mt][i][j] + bb);
          }
      } else {
        const int na = ntg - 16;       // head index
        const float bb = battn[na * 16 + lr];
#pragma unroll
        for (int mt = 0; mt < 2; ++mt)
#pragma unroll
          for (int j = 0; j < 4; ++j) {
            const int row = mt * 16 + lgrp * 4 + j;
            const float v = acc[mt][i][j] + bb;
            float m = v;
#pragma unroll
            for (int d_ = 1; d_ <= 8; d_ <<= 1) m = fmaxf(m, __shfl_xor(m, d_, 16));
            const float e = __expf(v - m);
            float s = e;
#pragma unroll
            for (int d_ = 1; d_ <= 8; d_ <<= 1) s += __shfl_xor(s, d_, 16);
            attn[(row0 + row) * 128 + na * 16 + lr] = e / s;
          }
      }
    }
  }
}

// ---------------------------------------------------------------------------
// K3: deformable sampling v7 (R12-proven). FP16 value -> pure v_pk_fma_f16.
// ---------------------------------------------------------------------------
__global__ __launch_bounds__(256) void k_sample6(const unsigned short* __restrict__ valh,
                                                 const unsigned short* __restrict__ offbf,
                                                 const float* __restrict__ attn,
                                                 const float* __restrict__ refp,
                                                 unsigned short* __restrict__ src2bf) {
  __shared__ int4  sIdx[4][2][8][16];   // 16 KB
  __shared__ uint4 sWgt[4][2][8][16];   // 16 KB (4 x dup-half2)
  const int t = threadIdx.x;
  const int w = t >> 6, lane = t & 63;
  const int tok = lane >> 5, hg = (lane >> 2) & 7, li = lane & 3;
  const int B = blockIdx.x;
  const int bimg = (B & 7) >> 1;
  const int ii = ((B >> 3) << 1) + (B & 1);       // 0..679
  const long n = (long)bimg * SLEN + ii * 8 + w * 2 + tok;
  const long bOff = (long)bimg * SLEN;

  const int   WlA[4] = {64, 32, 16, 8};
  const float rWA[4] = {1.f / 64.f, 1.f / 32.f, 1.f / 16.f, 1.f / 8.f};
  const int   stA[4] = {0, 4096, 5120, 5376};

#pragma unroll
  for (int q = 0; q < 4; ++q) {       // level = q, point-in-level = li
    const int pt = q * 4 + li;
    const int Wi = WlA[q];
    const float Wf = (float)Wi, rW = rWA[q];
    const float rx = refp[(n * 4 + q) * 2 + 0];
    const float ry = refp[(n * 4 + q) * 2 + 1];
    const float aw = attn[n * 128 + hg * 16 + pt];
    const int oi = ((hg * 4 + q) * 4 + li) * 2;
    const unsigned int opk = *reinterpret_cast<const unsigned int*>(&offbf[n * 256 + oi]);
    const float ox = bf2f((unsigned short)(opk & 0xffff));
    const float oy = bf2f((unsigned short)(opk >> 16));
    const float px = (rx + ox * rW) * Wf - 0.5f;
    const float py = (ry + oy * rW) * Wf - 0.5f;
    const float x0f = floorf(px), y0f = floorf(py);
    const float fx = px - x0f, fy = py - y0f;
    const int x0 = (int)x0f, y0 = (int)y0f;
    int   ic[4];
    float wc[4];
#pragma unroll
    for (int c = 0; c < 4; ++c) {
      const int dx = c & 1, dy = c >> 1;
      const int xi = x0 + dx, yi = y0 + dy;
      const float cw = (dx ? fx : 1.f - fx) * (dy ? fy : 1.f - fy);
      const bool valid = (xi >= 0) && (xi < Wi) && (yi >= 0) && (yi < Wi);
      const int xc = min(max(xi, 0), Wi - 1);
      const int yc = min(max(yi, 0), Wi - 1);
      const long flat = stA[q] + yc * Wi + xc;
      ic[c] = (int)((bOff + flat) * DD + hg * DHD);
      wc[c] = aw * cw * (valid ? 1.f : 0.f);
    }
    const int slot = pt ^ hg;
    sIdx[w][tok][hg][slot] = make_int4(ic[0], ic[1], ic[2], ic[3]);
    sWgt[w][tok][hg][slot] = make_uint4(pack2h_dup(wc[0]), pack2h_dup(wc[1]),
                                        pack2h_dup(wc[2]), pack2h_dup(wc[3]));
  }
  __syncthreads();

  __half2 acc[4];
#pragma unroll
  for (int d = 0; d < 4; ++d) acc[d] = __float2half2_rn(0.f);
#pragma unroll 4
  for (int pt = 0; pt < 16; ++pt) {
    const int slot = pt ^ hg;
    const int4  ia = sIdx[w][tok][hg][slot];
    const uint4 wp = sWgt[w][tok][hg][slot];
    const uint4 u0 = *reinterpret_cast<const uint4*>(&valh[(long)ia.x + li * 8]);
    const uint4 u1 = *reinterpret_cast<const uint4*>(&valh[(long)ia.y + li * 8]);
    const uint4 u2 = *reinterpret_cast<const uint4*>(&valh[(long)ia.z + li * 8]);
    const uint4 u3 = *reinterpret_cast<const uint4*>(&valh[(long)ia.w + li * 8]);
    const __half2 w0 = u2h2(wp.x), w1 = u2h2(wp.y), w2 = u2h2(wp.z), w3 = u2h2(wp.w);
    acc[0] = __hfma2(u2h2(u0.x), w0, acc[0]);
    acc[1] = __hfma2(u2h2(u0.y), w0, acc[1]);
    acc[2] = __hfma2(u2h2(u0.z), w0, acc[2]);
    acc[3] = __hfma2(u2h2(u0.w), w0, acc[3]);
    acc[0] = __hfma2(u2h2(u1.x), w1, acc[0]);
    acc[1] = __hfma2(u2h2(u1.y), w1, acc[1]);
    acc[2] = __hfma2(u2h2(u1.z), w1, acc[2]);
    acc[3] = __hfma2(u2h2(u1.w), w1, acc[3]);
    acc[0] = __hfma2(u2h2(u2.x), w2, acc[0]);
    acc[1] = __hfma2(u2h2(u2.y), w2, acc[1]);
    acc[2] = __hfma2(u2h2(u2.z), w2, acc[2]);
    acc[3] = __hfma2(u2h2(u2.w), w2, acc[3]);
    acc[0] = __hfma2(u2h2(u3.x), w3, acc[0]);
    acc[1] = __hfma2(u2h2(u3.y), w3, acc[1]);
    acc[2] = __hfma2(u2h2(u3.z), w3, acc[2]);
    acc[3] = __hfma2(u2h2(u3.w), w3, acc[3]);
  }
  ushort8 o;
#pragma unroll
  for (int d = 0; d < 4; ++d) {
    o[2 * d]     = f2bf(__half2float(__low2half(acc[d])));
    o[2 * d + 1] = f2bf(__half2float(__high2half(acc[d])));
  }
  *reinterpret_cast<ushort8*>(&src2bf[n * DD + hg * DHD + li * 8]) = o;
}

// ---------------------------------------------------------------------------
// K4: xbf = bf16(LN1(src + src2bf @ W_out + b_out)). (R8-proven, 32-row)
// ---------------------------------------------------------------------------
__global__ __launch_bounds__(256) void k_outproj_mfma(const unsigned short* __restrict__ src2bf,
                                                      const unsigned short* __restrict__ Wof,
                                                      const float* __restrict__ bo,
                                                      const float* __restrict__ src,
                                                      const float* __restrict__ g1,
                                                      const float* __restrict__ b1g,
                                                      unsigned short* __restrict__ xbf) {
  __shared__ float rsum[32][4];
  __shared__ float rssq[32][4];
  const int t = threadIdx.x;
  const int w = t >> 6, lane = t & 63;
  const int lr = lane & 15, lgrp = lane >> 4;
  const long row0 = (long)blockIdx.x * 32;

  short8 af[2][8];
#pragma unroll
  for (int mt = 0; mt < 2; ++mt)
#pragma unroll
    for (int kt = 0; kt < 8; ++kt)
      af[mt][kt] = *reinterpret_cast<const short8*>(
          &src2bf[(row0 + mt * 16 + lr) * DD + kt * 32 + lgrp * 8]);

  f32x4 acc[2][4];
#pragma unroll
  for (int mt = 0; mt < 2; ++mt)
#pragma unroll
    for (int n = 0; n < 4; ++n) acc[mt][n] = (f32x4){0.f, 0.f, 0.f, 0.f};
#pragma unroll
  for (int n = 0; n < 4; ++n) {
    const int nt = w * 4 + n;
#pragma unroll
    for (int kt = 0; kt < 8; ++kt) {
      const short8 bf_ = *reinterpret_cast<const short8*>(&Wof[((nt * 8 + kt) * 64 + lane) * 8]);
#pragma unroll
      for (int mt = 0; mt < 2; ++mt)
        acc[mt][n] = __builtin_amdgcn_mfma_f32_16x16x32_bf16(af[mt][kt], bf_, acc[mt][n], 0, 0, 0);
    }
  }
  float bc[4], gc[4], bgc[4];
#pragma unroll
  for (int n = 0; n < 4; ++n) {
    const int col = w * 64 + n * 16 + lr;
    bc[n] = bo[col]; gc[n] = g1[col]; bgc[n] = b1g[col];
  }
  float vals[2][4][4];
#pragma unroll
  for (int mt = 0; mt < 2; ++mt)
#pragma unroll
    for (int j = 0; j < 4; ++j) {
      const int row = mt * 16 + lgrp * 4 + j;
      float s = 0.f, ss = 0.f;
#pragma unroll
      for (int n = 0; n < 4; ++n) {
        const int col = w * 64 + n * 16 + lr;
        const float v = acc[mt][n][j] + bc[n] + src[(row0 + row) * DD + col];
        vals[mt][n][j] = v;
        s += v; ss += v * v;
      }
#pragma unroll
      for (int m = 1; m <= 8; m <<= 1) { s += __shfl_xor(s, m, 64); ss += __shfl_xor(ss, m, 64); }
      if (lr == 0) { rsum[row][w] = s; rssq[row][w] = ss; }
    }
  __syncthreads();
#pragma unroll
  for (int mt = 0; mt < 2; ++mt)
#pragma unroll
    for (int j = 0; j < 4; ++j) {
      const int row = mt * 16 + lgrp * 4 + j;
      const float s  = rsum[row][0] + rsum[row][1] + rsum[row][2] + rsum[row][3];
      const float ss = rssq[row][0] + rssq[row][1] + rssq[row][2] + rssq[row][3];
      const float mean = s * (1.f / 256.f);
      const float inv  = rsqrtf(ss * (1.f / 256.f) - mean * mean + 1e-5f);
#pragma unroll
      for (int n = 0; n < 4; ++n) {
        const int col = w * 64 + n * 16 + lr;
        xbf[(row0 + row) * DD + col] = f2bf((vals[mt][n][j] - mean) * inv * gc[n] + bgc[n]);
      }
    }
}

// ---------------------------------------------------------------------------
// K5a: H in TILED layout, XCD co-location swizzle (R17-proven). NEW:
// explicit double-buffered operand prefetch — kt+1's 8 loads issue BEFORE
// kt's 16 MFMAs (R17 showed VGPR=80 left zero prefetch registers; the
// serial load->MFMA chain was the wall).
// ---------------------------------------------------------------------------
__global__ __launch_bounds__(256) void k_ffn1e(const unsigned short* __restrict__ xbf,
                                               const unsigned short* __restrict__ W1f,
                                               const float* __restrict__ b1v,
                                               unsigned short* __restrict__ hfrag) {
  const int t = threadIdx.x;
  const int w = t >> 6, lane = t & 63;
  const int lr = lane & 15, lgrp = lane >> 4;
  const int bid = blockIdx.x;
  int x, hg;
  if (bid < 1344) { x = (bid & 7) + 8 * (bid >> 5); hg = (bid >> 3) & 3; }
  else            { const int rr = bid - 1344; x = 336 + (rr & 3); hg = rr >> 2; }
  const long row0 = (long)x * 64;

  f32x4 acc[4][4];                          // [mm=hd tile][n=token tile]
#pragma unroll
  for (int mm = 0; mm < 4; ++mm)
#pragma unroll
    for (int n = 0; n < 4; ++n) acc[mm][n] = (f32x4){0.f, 0.f, 0.f, 0.f};

  // double-buffered operands: cur/nxt
  short8 bxA[4], bxB[4], awA[4], awB[4];
#pragma unroll
  for (int n = 0; n < 4; ++n)
    bxA[n] = *reinterpret_cast<const short8*>(
        &xbf[(row0 + n * 16 + lr) * DD + 0 * 32 + lgrp * 8]);
#pragma unroll
  for (int mm = 0; mm < 4; ++mm) {
    const int ntg = hg * 16 + w * 4 + mm;
    awA[mm] = *reinterpret_cast<const short8*>(&W1f[((ntg * 8 + 0) * 64 + lane) * 8]);
  }

#pragma unroll
  for (int kt = 0; kt < 8; ++kt) {
    const bool even = (kt & 1) == 0;
    short8* bx = even ? bxA : bxB;
    short8* aw = even ? awA : awB;
    short8* bxn = even ? bxB : bxA;
    short8* awn = even ? awB : awA;
    if (kt < 7) {
      // issue next-kt loads BEFORE this kt's MFMAs
#pragma unroll
      for (int n = 0; n < 4; ++n)
        bxn[n] = *reinterpret_cast<const short8*>(
            &xbf[(row0 + n * 16 + lr) * DD + (kt + 1) * 32 + lgrp * 8]);
#pragma unroll
      for (int mm = 0; mm < 4; ++mm) {
        const int ntg = hg * 16 + w * 4 + mm;
        awn[mm] = *reinterpret_cast<const short8*>(
            &W1f[((ntg * 8 + kt + 1) * 64 + lane) * 8]);
      }
    }
#pragma unroll
    for (int mm = 0; mm < 4; ++mm)
#pragma unroll
      for (int n = 0; n < 4; ++n)
        acc[mm][n] = __builtin_amdgcn_mfma_f32_16x16x32_bf16(aw[mm], bx[n], acc[mm][n], 0, 0, 0);
  }

#pragma unroll
  for (int mm = 0; mm < 4; ++mm) {
    const int ht = hg * 16 + w * 4 + mm;                      // hd-tile 0..63
    const float4 bq = *reinterpret_cast<const float4*>(&b1v[ht * 16 + lgrp * 4]);
#pragma unroll
    for (int n = 0; n < 4; ++n) {
      const long tt = (long)x * 4 + n;                        // token-tile
      const long tbase = (tt * 64 + ht) * 256;
      int2 pk;
      pk.x = (int)pack2bf(fmaxf(acc[mm][n][0] + bq.x, 0.f),
                          fmaxf(acc[mm][n][1] + bq.y, 0.f));
      pk.y = (int)pack2bf(fmaxf(acc[mm][n][2] + bq.z, 0.f),
                          fmaxf(acc[mm][n][3] + bq.w, 0.f));
      *reinterpret_cast<int2*>(&hfrag[tbase + lane * 4]) = pk;
    }
  }
}

// ---------------------------------------------------------------------------
// K5b: out = LN2(xbf + H @ W2 + b2). (R16-proven: plain H loads, nt out store)
// ---------------------------------------------------------------------------
__global__ __launch_bounds__(256) void k_ffn2t(const unsigned short* __restrict__ hfrag,
                                               const unsigned short* __restrict__ W2f,
                                               const float* __restrict__ b2v_,
                                               const unsigned short* __restrict__ xbf,
                                               const float* __restrict__ g2,
                                               const float* __restrict__ b2g,
                                               float* __restrict__ outp) {
  __shared__ float rsum[32][4];
  __shared__ float rssq[32][4];
  const int t = threadIdx.x;
  const int w = t >> 6, lane = t & 63;
  const int lr = lane & 15, lgrp = lane >> 4;
  const long row0 = (long)blockIdx.x * 32;

  f32x4 acc[2][4];
#pragma unroll
  for (int mt = 0; mt < 2; ++mt)
#pragma unroll
    for (int n = 0; n < 4; ++n) acc[mt][n] = (f32x4){0.f, 0.f, 0.f, 0.f};

#pragma unroll 4
  for (int kt = 0; kt < 32; ++kt) {
    short8 ha[2];
#pragma unroll
    for (int mt = 0; mt < 2; ++mt) {
      const long tt = (row0 >> 4) + mt;
      const long tb = (tt * 64 + kt * 2 + (lgrp >> 1)) * 256;
      const unsigned short* tp = &hfrag[tb + (lgrp & 1) * 128 + lr * 4];
      union { short8 s8; struct { int2 lo, hi; } p; } u;
      u.p.lo = *reinterpret_cast<const int2*>(tp);        // i 0..3
      u.p.hi = *reinterpret_cast<const int2*>(tp + 64);   // i 4..7
      ha[mt] = u.s8;
    }
#pragma unroll
    for (int n = 0; n < 4; ++n) {
      const int nt = w * 4 + n;
      const short8 bf_ = *reinterpret_cast<const short8*>(&W2f[((nt * 32 + kt) * 64 + lane) * 8]);
#pragma unroll
      for (int mt = 0; mt < 2; ++mt)
        acc[mt][n] = __builtin_amdgcn_mfma_f32_16x16x32_bf16(ha[mt], bf_, acc[mt][n], 0, 0, 0);
    }
  }

  float b2c[4], g2c[4], bgc[4];
#pragma unroll
  for (int n = 0; n < 4; ++n) {
    const int col = w * 64 + n * 16 + lr;
    b2c[n] = b2v_[col]; g2c[n] = g2[col]; bgc[n] = b2g[col];
  }
  float vals[2][4][4];
#pragma unroll
  for (int mt = 0; mt < 2; ++mt)
#pragma unroll
    for (int j = 0; j < 4; ++j) {
      const int row = mt * 16 + lgrp * 4 + j;
      float s = 0.f, ss = 0.f;
#pragma unroll
      for (int n = 0; n < 4; ++n) {
        const int col = w * 64 + n * 16 + lr;
        const float v = acc[mt][n][j] + b2c[n] + bf2f(xbf[(row0 + row) * DD + col]);
        vals[mt][n][j] = v;
        s += v; ss += v * v;
      }
#pragma unroll
      for (int m = 1; m <= 8; m <<= 1) { s += __shfl_xor(s, m, 64); ss += __shfl_xor(ss, m, 64); }
      if (lr == 0) { rsum[row][w] = s; rssq[row][w] = ss; }
    }
  __syncthreads();
#pragma unroll
  for (int mt = 0; mt < 2; ++mt)
#pragma unroll
    for (int j = 0; j < 4; ++j) {
      const int row = mt * 16 + lgrp * 4 + j;
      const float s  = rsum[row][0] + rsum[row][1] + rsum[row][2] + rsum[row][3];
      const float ss = rssq[row][0] + rssq[row][1] + rssq[row][2] + rssq[row][3];
      const float mean = s * (1.f / 256.f);
      const float inv  = rsqrtf(ss * (1.f / 256.f) - mean * mean + 1e-5f);
#pragma unroll
      for (int n = 0; n < 4; ++n) {
        const int col = w * 64 + n * 16 + lr;
        __builtin_nontemporal_store((vals[mt][n][j] - mean) * inv * g2c[n] + bgc[n],
                                    &outp[(row0 + row) * DD + col]);
      }
    }
}

extern "C" void kernel_launch(void* const* d_in, const int* in_sizes, int n_in,
                              void* d_out, int out_size, void* d_ws, size_t ws_size,
                              hipStream_t stream) {
  const float* src  = (const float*)d_in[0];
  const float* refp = (const float*)d_in[1];
  const float* pos  = (const float*)d_in[5];
  const float* Wv   = (const float*)d_in[6];
  const float* bv   = (const float*)d_in[7];
  const float* Woff = (const float*)d_in[8];
  const float* boff = (const float*)d_in[9];
  const float* Wat  = (const float*)d_in[10];
  const float* bat  = (const float*)d_in[11];
  const float* Wo   = (const float*)d_in[12];
  const float* bo   = (const float*)d_in[13];
  const float* g1   = (const float*)d_in[14];
  const float* b1g  = (const float*)d_in[15];
  const float* W1   = (const float*)d_in[16];
  const float* b1f  = (const float*)d_in[17];
  const float* W2   = (const float*)d_in[18];
  const float* b2f  = (const float*)d_in[19];
  const float* g2   = (const float*)d_in[20];
  const float* b2g  = (const float*)d_in[21];
  float* out = (float*)d_out;

  // workspace layout (R13-proven):
  unsigned short* valh   = (unsigned short*)d_ws;       // NTOK*256 u16 (fp16)
  unsigned short* offbf  = valh + NTOK * 256;           // NTOK*256 u16
  float*          attn   = (float*)(offbf + NTOK * 256);// NTOK*128 f32
  unsigned short* src2bf = (unsigned short*)(attn + NTOK * 128); // NTOK*256 u16
  unsigned short* xbf    = src2bf + NTOK * 256;         // NTOK*256 u16
  unsigned short* W1f = xbf + NTOK * 256;               // 262144
  unsigned short* W2f = W1f + 262144;                   // 262144
  unsigned short* Wvf = W2f + 262144;                   // 65536
  unsigned short* Wqf = Wvf + 65536;                    // 98304
  unsigned short* Wof = Wqf + 98304;                    // 65536
  unsigned short* frag_end = Wof + 65536;
  const size_t used  = (size_t)((char*)frag_end - (char*)d_ws);
  const size_t hneed = (size_t)NTOK * 1024 * 2;
  unsigned short* hfrag = (used + hneed <= ws_size) ? frag_end
                                                    : (unsigned short*)d_ws;

  hipLaunchKernelGGL(k_prep_all, dim3(2944), dim3(256), 0, stream,
                     W1, W2, Wv, Woff, Wat, Wo, W1f, W2f, Wvf, Wqf, Wof);
  hipLaunchKernelGGL(k_vq2, dim3((int)(NTOK / 32)), dim3(256), 0, stream,
                     src, pos, Wvf, bv, Wqf, boff, bat, valh, offbf, attn);
  hipLaunchKernelGGL(k_sample6, dim3((int)(NTOK / 8)), dim3(256), 0, stream,
                     valh, offbf, attn, refp, src2bf);
  hipLaunchKernelGGL(k_outproj_mfma, dim3((int)(NTOK / 32)), dim3(256), 0, stream,
                     src2bf, Wof, bo, src, g1, b1g, xbf);
  hipLaunchKernelGGL(k_ffn1e, dim3(1360), dim3(256), 0, stream,
                     xbf, W1f, b1f, hfrag);
  hipLaunchKernelGGL(k_ffn2t, dim3((int)(NTOK / 32)), dim3(256), 0, stream,
                     hfrag, W2f, b2f, xbf, g2, b2g, out);
}